// Round 1
// baseline (534.467 us; speedup 1.0000x reference)
//
#include <hip/hip_runtime.h>
#include <hip/hip_bf16.h>

#define D 128
#define C 16

// ---------------------------------------------------------------- setup kernels

__global__ void k_init(int* counts, int* cursor, int N) {
    int i = blockIdx.x * blockDim.x + threadIdx.x;
    if (i < N) { counts[i] = 1; cursor[i] = 0; }   // self-loop counted
}

__global__ void k_hist(const int* __restrict__ dst, int* counts, int E) {
    int e = blockIdx.x * blockDim.x + threadIdx.x;
    if (e < E) atomicAdd(&counts[dst[e]], 1);
}

// single-block exclusive scan over counts -> row_ptr (N+1)
__global__ void k_scan(const int* __restrict__ counts, int* row_ptr, int N, int Et) {
    __shared__ int lds[1024];
    __shared__ int carry_s;
    int tid = threadIdx.x;
    if (tid == 0) carry_s = 0;
    __syncthreads();
    for (int base = 0; base < N; base += 1024) {
        int i = base + tid;
        int v = (i < N) ? counts[i] : 0;
        lds[tid] = v;
        __syncthreads();
        for (int off = 1; off < 1024; off <<= 1) {
            int t = (tid >= off) ? lds[tid - off] : 0;
            __syncthreads();
            lds[tid] += t;
            __syncthreads();
        }
        int incl = lds[tid];
        int carry = carry_s;
        if (i < N) row_ptr[i] = carry + incl - v;   // exclusive
        __syncthreads();
        if (tid == 1023) carry_s = carry + incl;
        __syncthreads();
    }
    if (tid == 0) row_ptr[N] = Et;
}

__global__ void k_dinv(const int* __restrict__ counts, float* dinv, int N) {
    int i = blockIdx.x * blockDim.x + threadIdx.x;
    if (i < N) {
        float d = (float)counts[i];
        dinv[i] = (d > 0.f) ? rsqrtf(d) : 0.f;
    }
}

__global__ void k_fill(const int* __restrict__ src, const int* __restrict__ dst,
                       const int* __restrict__ row_ptr, int* cursor, int* col,
                       int E, int N) {
    int e = blockIdx.x * blockDim.x + threadIdx.x;
    int Et = E + N;
    if (e >= Et) return;
    int s, d;
    if (e < E) { s = src[e]; d = dst[e]; }
    else       { s = d = e - E; }                  // self-loop
    int pos = row_ptr[d] + atomicAdd(&cursor[d], 1);
    col[pos] = s;
}

// h[i][:] = emb[x[i]][:]  (float4 granularity)
__global__ void k_embed(const int* __restrict__ x, const float* __restrict__ emb,
                        float* __restrict__ h, int N) {
    long idx = (long)blockIdx.x * blockDim.x + threadIdx.x;   // over N*32 float4
    if (idx >= (long)N * (D / 4)) return;
    int row = (int)(idx >> 5);
    int j   = (int)(idx & 31);
    int xr  = x[row];
    ((float4*)h)[(size_t)row * (D / 4) + j] =
        ((const float4*)emb)[(size_t)xr * (D / 4) + j];
}

// ---------------------------------------------------------------- aggregation
// one wave per destination node; lane holds 2 columns (float2)
__global__ __launch_bounds__(256) void k_agg(const float* __restrict__ h,
                                             const int* __restrict__ row_ptr,
                                             const int* __restrict__ col,
                                             const float* __restrict__ dinv,
                                             float* __restrict__ out, int N) {
    int wave = (int)((blockIdx.x * (long)blockDim.x + threadIdx.x) >> 6);
    int lane = threadIdx.x & 63;
    if (wave >= N) return;
    int v = wave;
    int s0 = row_ptr[v], s1 = row_ptr[v + 1];
    float dv = dinv[v];
    float ax = 0.f, ay = 0.f;
    int e = s0;
    for (; e + 1 < s1; e += 2) {
        int   c0 = col[e],      c1 = col[e + 1];
        float n0 = dinv[c0] * dv, n1 = dinv[c1] * dv;
        float2 h0 = *reinterpret_cast<const float2*>(h + (size_t)c0 * D + lane * 2);
        float2 h1 = *reinterpret_cast<const float2*>(h + (size_t)c1 * D + lane * 2);
        ax += h0.x * n0 + h1.x * n1;
        ay += h0.y * n0 + h1.y * n1;
    }
    if (e < s1) {
        int   c0 = col[e];
        float n0 = dinv[c0] * dv;
        float2 h0 = *reinterpret_cast<const float2*>(h + (size_t)c0 * D + lane * 2);
        ax += h0.x * n0;
        ay += h0.y * n0;
    }
    float2 r = make_float2(ax, ay);
    *reinterpret_cast<float2*>(out + (size_t)v * D + lane * 2) = r;
}

// ---------------------------------------------------------------- dense GEMM
// hout[row][:] = relu(hin[row][:] @ W + b) ; W (128x128) staged in LDS
__global__ __launch_bounds__(256) void k_gemm_relu(const float* __restrict__ hin,
                                                   const float* __restrict__ W,
                                                   const float* __restrict__ b,
                                                   float* __restrict__ hout, int N) {
    __shared__ float ldsW[D * D];       // 64 KB
    __shared__ float ldsH[4][D];        // 2 KB
    int tid = threadIdx.x;
    const float4* W4 = (const float4*)W;
    float4* L4 = (float4*)ldsW;
    for (int i = tid; i < (D * D) / 4; i += 256) L4[i] = W4[i];
    __syncthreads();

    int wv = tid >> 6, lane = tid & 63;
    const int ROWS = 8;
    long base_row = ((long)blockIdx.x * 4 + wv) * ROWS;
    int c0 = lane * 2;

    for (int r = 0; r < ROWS; ++r) {
        long row = base_row + r;
        bool active = (row < N);
        if (active) {
            float2 hv = *reinterpret_cast<const float2*>(hin + row * D + c0);
            ldsH[wv][c0] = hv.x;
            ldsH[wv][c0 + 1] = hv.y;
        }
        __syncthreads();
        if (active) {
            float acc0 = 0.f, acc1 = 0.f;
            #pragma unroll 8
            for (int k = 0; k < D; ++k) {
                float hk = ldsH[wv][k];
                float2 w = *reinterpret_cast<const float2*>(&ldsW[k * D + c0]);
                acc0 += hk * w.x;
                acc1 += hk * w.y;
            }
            float o0 = acc0 + b[c0];
            float o1 = acc1 + b[c0 + 1];
            o0 = o0 > 0.f ? o0 : 0.f;
            o1 = o1 > 0.f ? o1 : 0.f;
            *reinterpret_cast<float2*>(hout + row * D + c0) = make_float2(o0, o1);
        }
        __syncthreads();
    }
}

// ---------------------------------------------------------------- classifier
// out[row][c] = h[row][:] @ Wc[:,c] + bc[c]
__global__ __launch_bounds__(256) void k_cls(const float* __restrict__ h,
                                             const float* __restrict__ Wc,
                                             const float* __restrict__ bc,
                                             float* __restrict__ out, int N) {
    __shared__ float lWc[D * C];   // 8 KB
    __shared__ float lb[C];
    int tid = threadIdx.x;
    for (int i = tid; i < D * C; i += 256) lWc[i] = Wc[i];
    if (tid < C) lb[tid] = bc[tid];
    __syncthreads();
    long idx = (long)blockIdx.x * 256 + tid;     // over N*C
    if (idx >= (long)N * C) return;
    int row = (int)(idx >> 4);
    int c   = (int)(idx & (C - 1));
    const float* hr = h + (size_t)row * D;
    float acc = 0.f;
    #pragma unroll
    for (int k = 0; k < D; ++k) acc += hr[k] * lWc[k * C + c];
    out[idx] = acc + lb[c];
}

// ---------------------------------------------------------------- launch

extern "C" void kernel_launch(void* const* d_in, const int* in_sizes, int n_in,
                              void* d_out, int out_size, void* d_ws, size_t ws_size,
                              hipStream_t stream) {
    const int*   x    = (const int*)  d_in[0];
    const int*   ei   = (const int*)  d_in[1];   // [2,E] flat: first E = src, next E = dst
    const float* emb  = (const float*)d_in[2];
    const float* W0   = (const float*)d_in[3];
    const float* b0   = (const float*)d_in[4];
    const float* W1   = (const float*)d_in[5];
    const float* b1   = (const float*)d_in[6];
    const float* Wc   = (const float*)d_in[7];
    const float* bc   = (const float*)d_in[8];
    float* out = (float*)d_out;

    const int N  = in_sizes[0];
    const int E  = in_sizes[1] / 2;
    const int Et = E + N;

    const int* src = ei;
    const int* dst = ei + E;

    // workspace carve-up (4B aligned, all sizes multiples of 4 floats where needed)
    char* p = (char*)d_ws;
    auto take = [&](size_t bytes) { char* q = p; p += (bytes + 255) & ~(size_t)255; return q; };
    int*   counts  = (int*)  take((size_t)N * 4);
    int*   cursor  = (int*)  take((size_t)N * 4);
    int*   row_ptr = (int*)  take((size_t)(N + 1) * 4);
    float* dinv    = (float*)take((size_t)N * 4);
    int*   col     = (int*)  take((size_t)Et * 4);
    float* hA      = (float*)take((size_t)N * D * 4);
    float* hB      = (float*)take((size_t)N * D * 4);

    const int BS = 256;
    // 1. degree counts (incl. self-loop)
    k_init<<<(N + BS - 1) / BS, BS, 0, stream>>>(counts, cursor, N);
    k_hist<<<(E + BS - 1) / BS, BS, 0, stream>>>(dst, counts, E);
    // 2. row_ptr = exclusive scan
    k_scan<<<1, 1024, 0, stream>>>(counts, row_ptr, N, Et);
    // 3. dinv
    k_dinv<<<(N + BS - 1) / BS, BS, 0, stream>>>(counts, dinv, N);
    // 4. CSR fill (edges + self-loops)
    k_fill<<<(Et + BS - 1) / BS, BS, 0, stream>>>(src, dst, row_ptr, cursor, col, E, N);
    // 5. h0 = emb[x]
    k_embed<<<((long)N * (D / 4) + BS - 1) / BS, BS, 0, stream>>>(x, emb, hA, N);

    // layer 0: hB = A*hA ; hA = relu(hB@W0 + b0)
    k_agg<<<(N + 3) / 4, BS, 0, stream>>>(hA, row_ptr, col, dinv, hB, N);
    k_gemm_relu<<<(N + 31) / 32, BS, 0, stream>>>(hB, W0, b0, hA, N);
    // layer 1
    k_agg<<<(N + 3) / 4, BS, 0, stream>>>(hA, row_ptr, col, dinv, hB, N);
    k_gemm_relu<<<(N + 31) / 32, BS, 0, stream>>>(hB, W1, b1, hA, N);
    // classifier
    k_cls<<<((long)N * C + BS - 1) / BS, BS, 0, stream>>>(hA, Wc, bc, out, N);
}

// Round 2
// 353.183 us; speedup vs baseline: 1.5133x; 1.5133x over previous
//
#include <hip/hip_runtime.h>
#include <hip/hip_bf16.h>

#define D 128
#define C 16

// ---------------------------------------------------------------- setup kernels

__global__ void k_init(int* counts, int* cursor, int N) {
    int i = blockIdx.x * blockDim.x + threadIdx.x;
    if (i < N) { counts[i] = 1; cursor[i] = 0; }   // self-loop counted
}

__global__ void k_hist(const int* __restrict__ dst, int* counts, int E) {
    int e = blockIdx.x * blockDim.x + threadIdx.x;
    if (e < E) atomicAdd(&counts[dst[e]], 1);
}

// ---- 3-kernel parallel exclusive scan: counts -> row_ptr ----
// pass 1: per-block (1024) local exclusive scan + block total
__global__ __launch_bounds__(1024) void k_scan1(const int* __restrict__ counts,
                                                int* row_ptr, int* partial, int N) {
    __shared__ int lds[1024];
    int tid = threadIdx.x;
    int i = blockIdx.x * 1024 + tid;
    int v = (i < N) ? counts[i] : 0;
    lds[tid] = v;
    __syncthreads();
    for (int off = 1; off < 1024; off <<= 1) {
        int t = (tid >= off) ? lds[tid - off] : 0;
        __syncthreads();
        lds[tid] += t;
        __syncthreads();
    }
    int incl = lds[tid];
    if (i < N) row_ptr[i] = incl - v;           // block-local exclusive
    if (tid == 1023) partial[blockIdx.x] = incl;
}

// pass 2: scan the (<=64) block partials with one wave
__global__ void k_scan2(int* partial, int G) {
    int lane = threadIdx.x & 63;
    int v = (lane < G) ? partial[lane] : 0;
    int orig = v;
    #pragma unroll
    for (int d = 1; d < 64; d <<= 1) {
        int t = __shfl_up(v, d);
        if (lane >= d) v += t;
    }
    if (lane < G) partial[lane] = v - orig;     // exclusive
}

// pass 3: add block offsets; also write row_ptr[N]
__global__ __launch_bounds__(1024) void k_scan3(int* row_ptr, const int* __restrict__ partial,
                                                int N, int Et) {
    int i = blockIdx.x * 1024 + threadIdx.x;
    if (i < N) row_ptr[i] += partial[blockIdx.x];
    if (i == 0) row_ptr[N] = Et;
}

__global__ void k_dinv(const int* __restrict__ counts, float* dinv, int N) {
    int i = blockIdx.x * blockDim.x + threadIdx.x;
    if (i < N) {
        float d = (float)counts[i];
        dinv[i] = (d > 0.f) ? rsqrtf(d) : 0.f;
    }
}

__global__ void k_fill(const int* __restrict__ src, const int* __restrict__ dst,
                       const int* __restrict__ row_ptr, int* cursor, int* col,
                       int E, int N) {
    int e = blockIdx.x * blockDim.x + threadIdx.x;
    int Et = E + N;
    if (e >= Et) return;
    int s, d;
    if (e < E) { s = src[e]; d = dst[e]; }
    else       { s = d = e - E; }                  // self-loop
    int pos = row_ptr[d] + atomicAdd(&cursor[d], 1);
    col[pos] = s;
}

// h[i][:] = emb[x[i]][:]  (float4 granularity)
__global__ void k_embed(const int* __restrict__ x, const float* __restrict__ emb,
                        float* __restrict__ h, int N) {
    long idx = (long)blockIdx.x * blockDim.x + threadIdx.x;   // over N*32 float4
    if (idx >= (long)N * (D / 4)) return;
    int row = (int)(idx >> 5);
    int j   = (int)(idx & 31);
    int xr  = x[row];
    ((float4*)h)[(size_t)row * (D / 4) + j] =
        ((const float4*)emb)[(size_t)xr * (D / 4) + j];
}

// ---------------------------------------------------------------- aggregation
// one wave per destination node; lane holds 2 columns (float2)
__global__ __launch_bounds__(256) void k_agg(const float* __restrict__ h,
                                             const int* __restrict__ row_ptr,
                                             const int* __restrict__ col,
                                             const float* __restrict__ dinv,
                                             float* __restrict__ out, int N) {
    int wave = (int)((blockIdx.x * (long)blockDim.x + threadIdx.x) >> 6);
    int lane = threadIdx.x & 63;
    if (wave >= N) return;
    int v = wave;
    int s0 = row_ptr[v], s1 = row_ptr[v + 1];
    float dv = dinv[v];
    float ax = 0.f, ay = 0.f;
    int e = s0;
    for (; e + 1 < s1; e += 2) {
        int   c0 = col[e],      c1 = col[e + 1];
        float n0 = dinv[c0] * dv, n1 = dinv[c1] * dv;
        float2 h0 = *reinterpret_cast<const float2*>(h + (size_t)c0 * D + lane * 2);
        float2 h1 = *reinterpret_cast<const float2*>(h + (size_t)c1 * D + lane * 2);
        ax += h0.x * n0 + h1.x * n1;
        ay += h0.y * n0 + h1.y * n1;
    }
    if (e < s1) {
        int   c0 = col[e];
        float n0 = dinv[c0] * dv;
        float2 h0 = *reinterpret_cast<const float2*>(h + (size_t)c0 * D + lane * 2);
        ax += h0.x * n0;
        ay += h0.y * n0;
    }
    float2 r = make_float2(ax, ay);
    *reinterpret_cast<float2*>(out + (size_t)v * D + lane * 2) = r;
}

// ---------------------------------------------------------------- dense GEMM
// hout = relu(hin @ W + b).  lane = row, wave = 32-col chunk.
// W and b are read via wave-uniform addresses -> scalar (s_load) path:
// inner loop is 32 independent v_fma with SGPR second operand. No LDS.
__global__ __launch_bounds__(256) void k_gemm_relu(const float* __restrict__ hin,
                                                   const float* __restrict__ W,
                                                   const float* __restrict__ b,
                                                   float* __restrict__ hout, int N) {
    int lane  = threadIdx.x & 63;
    int chunk = __builtin_amdgcn_readfirstlane((int)(threadIdx.x >> 6)); // 0..3, SGPR
    long row = (long)blockIdx.x * 64 + lane;
    long rr  = (row < N) ? row : (long)(N - 1);

    // h row -> 128 VGPRs
    float4 hreg[32];
    const float4* hr = (const float4*)(hin + (size_t)rr * D);
    #pragma unroll
    for (int i = 0; i < 32; ++i) hreg[i] = hr[i];

    const float* Wb = W + chunk * 32;      // uniform base
    const float* bb = b + chunk * 32;

    float acc[32];
    #pragma unroll
    for (int j = 0; j < 32; ++j) acc[j] = bb[j];   // uniform -> s_load

    auto kstep = [&](float hk, int k) {
        const float* wr = Wb + (size_t)k * D;      // uniform address
        #pragma unroll
        for (int j = 0; j < 32; ++j) acc[j] = fmaf(hk, wr[j], acc[j]);
    };

    #pragma unroll
    for (int k4 = 0; k4 < 32; ++k4) {
        float4 hv = hreg[k4];
        kstep(hv.x, 4 * k4 + 0);
        kstep(hv.y, 4 * k4 + 1);
        kstep(hv.z, 4 * k4 + 2);
        kstep(hv.w, 4 * k4 + 3);
    }

    if (row < N) {
        float* o = hout + (size_t)row * D + chunk * 32;
        #pragma unroll
        for (int j4 = 0; j4 < 8; ++j4) {
            float4 v;
            v.x = fmaxf(acc[4 * j4 + 0], 0.f);
            v.y = fmaxf(acc[4 * j4 + 1], 0.f);
            v.z = fmaxf(acc[4 * j4 + 2], 0.f);
            v.w = fmaxf(acc[4 * j4 + 3], 0.f);
            *reinterpret_cast<float4*>(o + j4 * 4) = v;
        }
    }
}

// ---------------------------------------------------------------- classifier
// out[row][c] = h[row][:] @ Wc[:,c] + bc[c]
__global__ __launch_bounds__(256) void k_cls(const float* __restrict__ h,
                                             const float* __restrict__ Wc,
                                             const float* __restrict__ bc,
                                             float* __restrict__ out, int N) {
    __shared__ float lWc[D * C];   // 8 KB
    __shared__ float lb[C];
    int tid = threadIdx.x;
    for (int i = tid; i < D * C; i += 256) lWc[i] = Wc[i];
    if (tid < C) lb[tid] = bc[tid];
    __syncthreads();
    long idx = (long)blockIdx.x * 256 + tid;     // over N*C
    if (idx >= (long)N * C) return;
    int row = (int)(idx >> 4);
    int c   = (int)(idx & (C - 1));
    const float* hr = h + (size_t)row * D;
    float acc = 0.f;
    #pragma unroll
    for (int k = 0; k < D; ++k) acc += hr[k] * lWc[k * C + c];
    out[idx] = acc + lb[c];
}

// ---------------------------------------------------------------- launch

extern "C" void kernel_launch(void* const* d_in, const int* in_sizes, int n_in,
                              void* d_out, int out_size, void* d_ws, size_t ws_size,
                              hipStream_t stream) {
    const int*   x    = (const int*)  d_in[0];
    const int*   ei   = (const int*)  d_in[1];   // [2,E] flat: first E = src, next E = dst
    const float* emb  = (const float*)d_in[2];
    const float* W0   = (const float*)d_in[3];
    const float* b0   = (const float*)d_in[4];
    const float* W1   = (const float*)d_in[5];
    const float* b1   = (const float*)d_in[6];
    const float* Wc   = (const float*)d_in[7];
    const float* bc   = (const float*)d_in[8];
    float* out = (float*)d_out;

    const int N  = in_sizes[0];
    const int E  = in_sizes[1] / 2;
    const int Et = E + N;

    const int* src = ei;
    const int* dst = ei + E;

    // workspace carve-up
    char* p = (char*)d_ws;
    auto take = [&](size_t bytes) { char* q = p; p += (bytes + 255) & ~(size_t)255; return q; };
    int*   counts  = (int*)  take((size_t)N * 4);
    int*   cursor  = (int*)  take((size_t)N * 4);
    int*   row_ptr = (int*)  take((size_t)(N + 1) * 4);
    float* dinv    = (float*)take((size_t)N * 4);
    int*   partial = (int*)  take((size_t)1024 * 4);
    int*   col     = (int*)  take((size_t)Et * 4);
    float* hA      = (float*)take((size_t)N * D * 4);
    float* hB      = (float*)take((size_t)N * D * 4);

    const int BS = 256;
    const int G  = (N + 1023) / 1024;            // scan blocks (<=64 for N<=65536)

    // 1. degree counts (incl. self-loop)
    k_init<<<(N + BS - 1) / BS, BS, 0, stream>>>(counts, cursor, N);
    k_hist<<<(E + BS - 1) / BS, BS, 0, stream>>>(dst, counts, E);
    // 2. row_ptr = exclusive scan (parallel, 3 passes)
    k_scan1<<<G, 1024, 0, stream>>>(counts, row_ptr, partial, N);
    k_scan2<<<1, 64, 0, stream>>>(partial, G);
    k_scan3<<<G, 1024, 0, stream>>>(row_ptr, partial, N, Et);
    // 3. dinv
    k_dinv<<<(N + BS - 1) / BS, BS, 0, stream>>>(counts, dinv, N);
    // 4. CSR fill (edges + self-loops)
    k_fill<<<(Et + BS - 1) / BS, BS, 0, stream>>>(src, dst, row_ptr, cursor, col, E, N);
    // 5. h0 = emb[x]
    k_embed<<<((long)N * (D / 4) + BS - 1) / BS, BS, 0, stream>>>(x, emb, hA, N);

    // layer 0: hB = A*hA ; hA = relu(hB@W0 + b0)
    k_agg<<<(N + 3) / 4, BS, 0, stream>>>(hA, row_ptr, col, dinv, hB, N);
    k_gemm_relu<<<(N + 63) / 64, BS, 0, stream>>>(hB, W0, b0, hA, N);
    // layer 1
    k_agg<<<(N + 3) / 4, BS, 0, stream>>>(hA, row_ptr, col, dinv, hB, N);
    k_gemm_relu<<<(N + 63) / 64, BS, 0, stream>>>(hB, W1, b1, hA, N);
    // classifier
    k_cls<<<((long)N * C + BS - 1) / BS, BS, 0, stream>>>(hA, Wc, bc, out, N);
}

// Round 3
// 320.509 us; speedup vs baseline: 1.6676x; 1.1019x over previous
//
#include <hip/hip_runtime.h>
#include <hip/hip_bf16.h>

#define D 128
#define C 16

// ---------------------------------------------------------------- setup kernels

__global__ void k_init(int* counts, int* cursor, int N) {
    int i = blockIdx.x * blockDim.x + threadIdx.x;
    if (i < N) { counts[i] = 1; cursor[i] = 0; }   // self-loop counted
}

__global__ void k_hist(const int* __restrict__ dst, int* counts, int E) {
    int e = blockIdx.x * blockDim.x + threadIdx.x;
    if (e < E) atomicAdd(&counts[dst[e]], 1);
}

// ---- 3-kernel parallel exclusive scan: counts -> row_ptr ----
__global__ __launch_bounds__(1024) void k_scan1(const int* __restrict__ counts,
                                                int* row_ptr, int* partial, int N) {
    __shared__ int lds[1024];
    int tid = threadIdx.x;
    int i = blockIdx.x * 1024 + tid;
    int v = (i < N) ? counts[i] : 0;
    lds[tid] = v;
    __syncthreads();
    for (int off = 1; off < 1024; off <<= 1) {
        int t = (tid >= off) ? lds[tid - off] : 0;
        __syncthreads();
        lds[tid] += t;
        __syncthreads();
    }
    int incl = lds[tid];
    if (i < N) row_ptr[i] = incl - v;           // block-local exclusive
    if (tid == 1023) partial[blockIdx.x] = incl;
}

__global__ void k_scan2(int* partial, int G) {
    int lane = threadIdx.x & 63;
    int v = (lane < G) ? partial[lane] : 0;
    int orig = v;
    #pragma unroll
    for (int d = 1; d < 64; d <<= 1) {
        int t = __shfl_up(v, d);
        if (lane >= d) v += t;
    }
    if (lane < G) partial[lane] = v - orig;     // exclusive
}

__global__ __launch_bounds__(1024) void k_scan3(int* row_ptr, const int* __restrict__ partial,
                                                int N, int Et) {
    int i = blockIdx.x * 1024 + threadIdx.x;
    if (i < N) row_ptr[i] += partial[blockIdx.x];
    if (i == 0) row_ptr[N] = Et;
}

__global__ void k_dinv(const int* __restrict__ counts, float* dinv, int N) {
    int i = blockIdx.x * blockDim.x + threadIdx.x;
    if (i < N) {
        float d = (float)counts[i];
        dinv[i] = (d > 0.f) ? rsqrtf(d) : 0.f;
    }
}

__global__ void k_fill(const int* __restrict__ src, const int* __restrict__ dst,
                       const int* __restrict__ row_ptr, int* cursor, int* col,
                       int E, int N) {
    int e = blockIdx.x * blockDim.x + threadIdx.x;
    int Et = E + N;
    if (e >= Et) return;
    int s, d;
    if (e < E) { s = src[e]; d = dst[e]; }
    else       { s = d = e - E; }                  // self-loop
    int pos = row_ptr[d] + atomicAdd(&cursor[d], 1);
    col[pos] = s;
}

// h[i][:] = emb[x[i]][:]
__global__ void k_embed(const int* __restrict__ x, const float* __restrict__ emb,
                        float* __restrict__ h, int N) {
    long idx = (long)blockIdx.x * blockDim.x + threadIdx.x;   // over N*32 float4
    if (idx >= (long)N * (D / 4)) return;
    int row = (int)(idx >> 5);
    int j   = (int)(idx & 31);
    int xr  = x[row];
    ((float4*)h)[(size_t)row * (D / 4) + j] =
        ((const float4*)emb)[(size_t)xr * (D / 4) + j];
}

// ---------------------------------------------------------------- aggregation
// persistent waves, grid-stride over nodes; scalarized CSR walk; 4 gathers in flight
__global__ __launch_bounds__(256) void k_agg(const float* __restrict__ h,
                                             const int* __restrict__ row_ptr,
                                             const int* __restrict__ col,
                                             const float* __restrict__ dinv,
                                             float* __restrict__ out, int N, int nwaves) {
    int gwave = (int)((blockIdx.x * 256u + threadIdx.x) >> 6);
    int lane = threadIdx.x & 63;
    int cofs = lane * 2;

    for (int v = gwave; v < N; v += nwaves) {
        // wave-uniform row bounds -> scalar registers (s_load path for col/dinv)
        int s0 = __builtin_amdgcn_readfirstlane(row_ptr[v]);
        int s1 = __builtin_amdgcn_readfirstlane(row_ptr[v + 1]);
        float dv = dinv[v];
        float ax = 0.f, ay = 0.f;
        int e = s0;
        for (; e + 4 <= s1; e += 4) {
            int c0 = __builtin_amdgcn_readfirstlane(col[e]);
            int c1 = __builtin_amdgcn_readfirstlane(col[e + 1]);
            int c2 = __builtin_amdgcn_readfirstlane(col[e + 2]);
            int c3 = __builtin_amdgcn_readfirstlane(col[e + 3]);
            float n0 = dinv[c0] * dv, n1 = dinv[c1] * dv;
            float n2 = dinv[c2] * dv, n3 = dinv[c3] * dv;
            float2 h0 = *reinterpret_cast<const float2*>(h + (size_t)c0 * D + cofs);
            float2 h1 = *reinterpret_cast<const float2*>(h + (size_t)c1 * D + cofs);
            float2 h2 = *reinterpret_cast<const float2*>(h + (size_t)c2 * D + cofs);
            float2 h3 = *reinterpret_cast<const float2*>(h + (size_t)c3 * D + cofs);
            ax += h0.x * n0 + h1.x * n1 + h2.x * n2 + h3.x * n3;
            ay += h0.y * n0 + h1.y * n1 + h2.y * n2 + h3.y * n3;
        }
        for (; e < s1; ++e) {
            int c = __builtin_amdgcn_readfirstlane(col[e]);
            float n = dinv[c] * dv;
            float2 hv = *reinterpret_cast<const float2*>(h + (size_t)c * D + cofs);
            ax += hv.x * n;
            ay += hv.y * n;
        }
        *reinterpret_cast<float2*>(out + (size_t)v * D + cofs) = make_float2(ax, ay);
    }
}

// ---------------------------------------------------------------- dense GEMM
// hout = relu(hin @ W + b).  lane = row, wave = 32-col chunk. W via scalar loads.
__global__ __launch_bounds__(256) void k_gemm_relu(const float* __restrict__ hin,
                                                   const float* __restrict__ W,
                                                   const float* __restrict__ b,
                                                   float* __restrict__ hout, int N) {
    int lane  = threadIdx.x & 63;
    int chunk = __builtin_amdgcn_readfirstlane((int)(threadIdx.x >> 6)); // 0..3, SGPR
    long row = (long)blockIdx.x * 64 + lane;
    long rr  = (row < N) ? row : (long)(N - 1);

    float4 hreg[32];
    const float4* hr = (const float4*)(hin + (size_t)rr * D);
    #pragma unroll
    for (int i = 0; i < 32; ++i) hreg[i] = hr[i];

    const float* Wb = W + chunk * 32;
    const float* bb = b + chunk * 32;

    float acc[32];
    #pragma unroll
    for (int j = 0; j < 32; ++j) acc[j] = bb[j];

    auto kstep = [&](float hk, int k) {
        const float* wr = Wb + (size_t)k * D;
        #pragma unroll
        for (int j = 0; j < 32; ++j) acc[j] = fmaf(hk, wr[j], acc[j]);
    };

    #pragma unroll
    for (int k4 = 0; k4 < 32; ++k4) {
        float4 hv = hreg[k4];
        kstep(hv.x, 4 * k4 + 0);
        kstep(hv.y, 4 * k4 + 1);
        kstep(hv.z, 4 * k4 + 2);
        kstep(hv.w, 4 * k4 + 3);
    }

    if (row < N) {
        float* o = hout + (size_t)row * D + chunk * 32;
        #pragma unroll
        for (int j4 = 0; j4 < 8; ++j4) {
            float4 v;
            v.x = fmaxf(acc[4 * j4 + 0], 0.f);
            v.y = fmaxf(acc[4 * j4 + 1], 0.f);
            v.z = fmaxf(acc[4 * j4 + 2], 0.f);
            v.w = fmaxf(acc[4 * j4 + 3], 0.f);
            *reinterpret_cast<float4*>(o + j4 * 4) = v;
        }
    }
}

// ---------------------------------------------------------------- classifier
__global__ __launch_bounds__(256) void k_cls(const float* __restrict__ h,
                                             const float* __restrict__ Wc,
                                             const float* __restrict__ bc,
                                             float* __restrict__ out, int N) {
    __shared__ float lWc[D * C];   // 8 KB
    __shared__ float lb[C];
    int tid = threadIdx.x;
    for (int i = tid; i < D * C; i += 256) lWc[i] = Wc[i];
    if (tid < C) lb[tid] = bc[tid];
    __syncthreads();
    long idx = (long)blockIdx.x * 256 + tid;     // over N*C
    if (idx >= (long)N * C) return;
    int row = (int)(idx >> 4);
    int c   = (int)(idx & (C - 1));
    const float* hr = h + (size_t)row * D;
    float acc = 0.f;
    #pragma unroll
    for (int k = 0; k < D; ++k) acc += hr[k] * lWc[k * C + c];
    out[idx] = acc + lb[c];
}

// ---------------------------------------------------------------- launch

extern "C" void kernel_launch(void* const* d_in, const int* in_sizes, int n_in,
                              void* d_out, int out_size, void* d_ws, size_t ws_size,
                              hipStream_t stream) {
    const int*   x    = (const int*)  d_in[0];
    const int*   ei   = (const int*)  d_in[1];   // [2,E] flat: first E = src, next E = dst
    const float* emb  = (const float*)d_in[2];
    const float* W0   = (const float*)d_in[3];
    const float* b0   = (const float*)d_in[4];
    const float* W1   = (const float*)d_in[5];
    const float* b1   = (const float*)d_in[6];
    const float* Wc   = (const float*)d_in[7];
    const float* bc   = (const float*)d_in[8];
    float* out = (float*)d_out;

    const int N  = in_sizes[0];
    const int E  = in_sizes[1] / 2;
    const int Et = E + N;

    const int* src = ei;
    const int* dst = ei + E;

    char* p = (char*)d_ws;
    auto take = [&](size_t bytes) { char* q = p; p += (bytes + 255) & ~(size_t)255; return q; };
    int*   counts  = (int*)  take((size_t)N * 4);
    int*   cursor  = (int*)  take((size_t)N * 4);
    int*   row_ptr = (int*)  take((size_t)(N + 1) * 4);
    float* dinv    = (float*)take((size_t)N * 4);
    int*   partial = (int*)  take((size_t)1024 * 4);
    int*   col     = (int*)  take((size_t)Et * 4);
    float* hA      = (float*)take((size_t)N * D * 4);
    float* hB      = (float*)take((size_t)N * D * 4);

    const int BS = 256;
    const int G  = (N + 1023) / 1024;

    k_init<<<(N + BS - 1) / BS, BS, 0, stream>>>(counts, cursor, N);
    k_hist<<<(E + BS - 1) / BS, BS, 0, stream>>>(dst, counts, E);
    k_scan1<<<G, 1024, 0, stream>>>(counts, row_ptr, partial, N);
    k_scan2<<<1, 64, 0, stream>>>(partial, G);
    k_scan3<<<G, 1024, 0, stream>>>(row_ptr, partial, N, Et);
    k_dinv<<<(N + BS - 1) / BS, BS, 0, stream>>>(counts, dinv, N);
    k_fill<<<(Et + BS - 1) / BS, BS, 0, stream>>>(src, dst, row_ptr, cursor, col, E, N);
    k_embed<<<((long)N * (D / 4) + BS - 1) / BS, BS, 0, stream>>>(x, emb, hA, N);

    const int AGG_BLOCKS = 2048;                 // 8 blocks/CU, 32 waves/CU
    const int NWAVES = AGG_BLOCKS * 4;

    // layer 0
    k_agg<<<AGG_BLOCKS, BS, 0, stream>>>(hA, row_ptr, col, dinv, hB, N, NWAVES);
    k_gemm_relu<<<(N + 63) / 64, BS, 0, stream>>>(hB, W0, b0, hA, N);
    // layer 1
    k_agg<<<AGG_BLOCKS, BS, 0, stream>>>(hA, row_ptr, col, dinv, hB, N, NWAVES);
    k_gemm_relu<<<(N + 63) / 64, BS, 0, stream>>>(hB, W1, b1, hA, N);
    // classifier
    k_cls<<<((long)N * C + BS - 1) / BS, BS, 0, stream>>>(hA, Wc, bc, out, N);
}

// Round 4
// 288.161 us; speedup vs baseline: 1.8548x; 1.1123x over previous
//
#include <hip/hip_runtime.h>
#include <hip/hip_bf16.h>

#define D 128
#define C 16

typedef unsigned int uint;

// RNE pack of two fp32 -> bf16x2 in a uint (lo = a, hi = b)
__device__ __forceinline__ uint pack_bf16(float a, float b) {
    uint ua = __float_as_uint(a);
    uint ub = __float_as_uint(b);
    ua += 0x7fffu + ((ua >> 16) & 1u);
    ub += 0x7fffu + ((ub >> 16) & 1u);
    return (ua >> 16) | (ub & 0xffff0000u);
}
__device__ __forceinline__ float bf_lo(uint u) { return __uint_as_float(u << 16); }
__device__ __forceinline__ float bf_hi(uint u) { return __uint_as_float(u & 0xffff0000u); }

// ---------------------------------------------------------------- setup kernels

__global__ void k_init(int* counts, int* cursor, int N) {
    int i = blockIdx.x * blockDim.x + threadIdx.x;
    if (i < N) { counts[i] = 1; cursor[i] = 0; }   // self-loop counted
}

__global__ void k_hist(const int* __restrict__ dst, int* counts, int E) {
    int e = blockIdx.x * blockDim.x + threadIdx.x;
    if (e < E) atomicAdd(&counts[dst[e]], 1);
}

// ---- 3-kernel parallel exclusive scan: counts -> row_ptr ----
__global__ __launch_bounds__(1024) void k_scan1(const int* __restrict__ counts,
                                                int* row_ptr, int* partial, int N) {
    __shared__ int lds[1024];
    int tid = threadIdx.x;
    int i = blockIdx.x * 1024 + tid;
    int v = (i < N) ? counts[i] : 0;
    lds[tid] = v;
    __syncthreads();
    for (int off = 1; off < 1024; off <<= 1) {
        int t = (tid >= off) ? lds[tid - off] : 0;
        __syncthreads();
        lds[tid] += t;
        __syncthreads();
    }
    int incl = lds[tid];
    if (i < N) row_ptr[i] = incl - v;           // block-local exclusive
    if (tid == 1023) partial[blockIdx.x] = incl;
}

__global__ void k_scan2(int* partial, int G) {
    int lane = threadIdx.x & 63;
    int v = (lane < G) ? partial[lane] : 0;
    int orig = v;
    #pragma unroll
    for (int d = 1; d < 64; d <<= 1) {
        int t = __shfl_up(v, d);
        if (lane >= d) v += t;
    }
    if (lane < G) partial[lane] = v - orig;     // exclusive
}

__global__ __launch_bounds__(1024) void k_scan3(int* row_ptr, const int* __restrict__ partial,
                                                int N, int Et) {
    int i = blockIdx.x * 1024 + threadIdx.x;
    if (i < N) row_ptr[i] += partial[blockIdx.x];
    if (i == 0) row_ptr[N] = Et;
}

__global__ void k_dinv(const int* __restrict__ counts, float* dinv, int N) {
    int i = blockIdx.x * blockDim.x + threadIdx.x;
    if (i < N) {
        float d = (float)counts[i];
        dinv[i] = (d > 0.f) ? rsqrtf(d) : 0.f;
    }
}

__global__ void k_fill(const int* __restrict__ src, const int* __restrict__ dst,
                       const int* __restrict__ row_ptr, int* cursor, int* col,
                       int E, int N) {
    int e = blockIdx.x * blockDim.x + threadIdx.x;
    int Et = E + N;
    if (e >= Et) return;
    int s, d;
    if (e < E) { s = src[e]; d = dst[e]; }
    else       { s = d = e - E; }                  // self-loop
    int pos = row_ptr[d] + atomicAdd(&cursor[d], 1);
    col[pos] = s;
}

// h16[i][:] = bf16(emb[x[i]][:]) ; thread handles 8 values
__global__ void k_embed(const int* __restrict__ x, const float* __restrict__ emb,
                        uint* __restrict__ h16, int N) {
    long idx = (long)blockIdx.x * blockDim.x + threadIdx.x;   // over N*16
    if (idx >= (long)N * 16) return;
    int row = (int)(idx >> 4);
    int j8  = (int)(idx & 15);
    int xr  = x[row];
    const float4* e4 = (const float4*)(emb + (size_t)xr * D + j8 * 8);
    float4 a = e4[0], b = e4[1];
    uint4 o;
    o.x = pack_bf16(a.x, a.y);
    o.y = pack_bf16(a.z, a.w);
    o.z = pack_bf16(b.x, b.y);
    o.w = pack_bf16(b.z, b.w);
    ((uint4*)(h16 + (size_t)row * 64))[j8] = o;
}

// ---------------------------------------------------------------- aggregation
// persistent waves; bf16 h table (12.8 MB); 8 gathers in flight; fp32 accumulate
__global__ __launch_bounds__(256) void k_agg(const uint* __restrict__ h16,
                                             const int* __restrict__ row_ptr,
                                             const int* __restrict__ col,
                                             const float* __restrict__ dinv,
                                             uint* __restrict__ out16, int N, int nwaves) {
    int gwave = (int)((blockIdx.x * 256u + threadIdx.x) >> 6);
    int lane = threadIdx.x & 63;

    for (int v = gwave; v < N; v += nwaves) {
        int s0 = __builtin_amdgcn_readfirstlane(row_ptr[v]);
        int s1 = __builtin_amdgcn_readfirstlane(row_ptr[v + 1]);
        float dv = dinv[v];
        float ax = 0.f, ay = 0.f;
        int e = s0;
        for (; e + 8 <= s1; e += 8) {
            int c[8]; uint u[8]; float n[8];
            #pragma unroll
            for (int t = 0; t < 8; ++t) c[t] = __builtin_amdgcn_readfirstlane(col[e + t]);
            #pragma unroll
            for (int t = 0; t < 8; ++t) u[t] = h16[(size_t)c[t] * 64 + lane];
            #pragma unroll
            for (int t = 0; t < 8; ++t) n[t] = dinv[c[t]] * dv;
            #pragma unroll
            for (int t = 0; t < 8; ++t) {
                ax = fmaf(bf_lo(u[t]), n[t], ax);
                ay = fmaf(bf_hi(u[t]), n[t], ay);
            }
        }
        for (; e < s1; ++e) {
            int c = __builtin_amdgcn_readfirstlane(col[e]);
            float n = dinv[c] * dv;
            uint u = h16[(size_t)c * 64 + lane];
            ax = fmaf(bf_lo(u), n, ax);
            ay = fmaf(bf_hi(u), n, ay);
        }
        out16[(size_t)v * 64 + lane] = pack_bf16(ax, ay);
    }
}

// ---------------------------------------------------------------- dense GEMM
// lane = row, wave = 32-col chunk, W/b/Wc via wave-uniform (scalar) loads.
// FUSE=false: hout16 = bf16(relu(hin @ W + b))
// FUSE=true : outf = relu(hin @ W + b) @ Wc + bc   (classifier fused, no h2 write)
template<bool FUSE>
__global__ __launch_bounds__(256) void k_gemm(const uint* __restrict__ hin,   // bf16x2
                                              const float* __restrict__ W,
                                              const float* __restrict__ b,
                                              uint* __restrict__ hout16,
                                              const float* __restrict__ Wc,
                                              const float* __restrict__ bc,
                                              float* __restrict__ outf, int N) {
    int lane  = threadIdx.x & 63;
    int wv    = threadIdx.x >> 6;
    int chunk = __builtin_amdgcn_readfirstlane(wv); // 0..3, SGPR
    long row = (long)blockIdx.x * 64 + lane;
    long rr  = (row < N) ? row : (long)(N - 1);

    // h row (128 bf16 = 64 uints) -> 64 VGPRs
    uint4 hu[16];
    const uint4* hr = (const uint4*)(hin + (size_t)rr * 64);
    #pragma unroll
    for (int i = 0; i < 16; ++i) hu[i] = hr[i];

    const float* Wb = W + chunk * 32;
    const float* bb = b + chunk * 32;

    float acc[32];
    #pragma unroll
    for (int j = 0; j < 32; ++j) acc[j] = bb[j];

    auto kstep = [&](float hk, int k) {
        const float* wr = Wb + (size_t)k * D;      // uniform address -> s_load
        #pragma unroll
        for (int j = 0; j < 32; ++j) acc[j] = fmaf(hk, wr[j], acc[j]);
    };

    #pragma unroll
    for (int i = 0; i < 16; ++i) {
        uint4 q = hu[i];
        kstep(bf_lo(q.x), i * 8 + 0); kstep(bf_hi(q.x), i * 8 + 1);
        kstep(bf_lo(q.y), i * 8 + 2); kstep(bf_hi(q.y), i * 8 + 3);
        kstep(bf_lo(q.z), i * 8 + 4); kstep(bf_hi(q.z), i * 8 + 5);
        kstep(bf_lo(q.w), i * 8 + 6); kstep(bf_hi(q.w), i * 8 + 7);
    }

    if (!FUSE) {
        if (row < N) {
            uint o[16];
            #pragma unroll
            for (int j = 0; j < 16; ++j)
                o[j] = pack_bf16(fmaxf(acc[2 * j], 0.f), fmaxf(acc[2 * j + 1], 0.f));
            uint4* op = (uint4*)(hout16 + (size_t)row * 64 + chunk * 16);
            #pragma unroll
            for (int q4 = 0; q4 < 4; ++q4)
                op[q4] = make_uint4(o[4 * q4], o[4 * q4 + 1], o[4 * q4 + 2], o[4 * q4 + 3]);
        }
    } else {
        // per-wave partial logits over this chunk's 32 k-terms
        float pc[C];
        #pragma unroll
        for (int c2 = 0; c2 < C; ++c2) pc[c2] = 0.f;
        #pragma unroll
        for (int j = 0; j < 32; ++j) {
            float r = fmaxf(acc[j], 0.f);
            const float* wc = Wc + (size_t)(chunk * 32 + j) * C;   // uniform -> s_load
            #pragma unroll
            for (int c2 = 0; c2 < C; ++c2) pc[c2] = fmaf(r, wc[c2], pc[c2]);
        }
        __shared__ float red[4][64][C + 1];        // +1 pad: avoid bank conflicts
        #pragma unroll
        for (int c2 = 0; c2 < C; ++c2) red[wv][lane][c2] = pc[c2];
        __syncthreads();
        int o = threadIdx.x * 4;                   // 1024 outputs, 4 per thread
        #pragma unroll
        for (int t = 0; t < 4; ++t) {
            int oo = o + t;
            int r2 = oo >> 4, c2 = oo & (C - 1);
            long grow = (long)blockIdx.x * 64 + r2;
            if (grow < N) {
                float s = red[0][r2][c2] + red[1][r2][c2] +
                          red[2][r2][c2] + red[3][r2][c2] + bc[c2];
                outf[grow * C + c2] = s;
            }
        }
    }
}

// ---------------------------------------------------------------- launch

extern "C" void kernel_launch(void* const* d_in, const int* in_sizes, int n_in,
                              void* d_out, int out_size, void* d_ws, size_t ws_size,
                              hipStream_t stream) {
    const int*   x    = (const int*)  d_in[0];
    const int*   ei   = (const int*)  d_in[1];   // [2,E]: first E = src, next E = dst
    const float* emb  = (const float*)d_in[2];
    const float* W0   = (const float*)d_in[3];
    const float* b0   = (const float*)d_in[4];
    const float* W1   = (const float*)d_in[5];
    const float* b1   = (const float*)d_in[6];
    const float* Wc   = (const float*)d_in[7];
    const float* bc   = (const float*)d_in[8];
    float* out = (float*)d_out;

    const int N  = in_sizes[0];
    const int E  = in_sizes[1] / 2;
    const int Et = E + N;

    const int* src = ei;
    const int* dst = ei + E;

    char* p = (char*)d_ws;
    auto take = [&](size_t bytes) { char* q = p; p += (bytes + 255) & ~(size_t)255; return q; };
    int*   counts  = (int*)  take((size_t)N * 4);
    int*   cursor  = (int*)  take((size_t)N * 4);
    int*   row_ptr = (int*)  take((size_t)(N + 1) * 4);
    float* dinv    = (float*)take((size_t)N * 4);
    int*   partial = (int*)  take((size_t)1024 * 4);
    int*   col     = (int*)  take((size_t)Et * 4);
    uint*  hA16    = (uint*) take((size_t)N * 64 * 4);   // bf16 h table A
    uint*  hB16    = (uint*) take((size_t)N * 64 * 4);   // bf16 h table B

    const int BS = 256;
    const int G  = (N + 1023) / 1024;

    k_init<<<(N + BS - 1) / BS, BS, 0, stream>>>(counts, cursor, N);
    k_hist<<<(E + BS - 1) / BS, BS, 0, stream>>>(dst, counts, E);
    k_scan1<<<G, 1024, 0, stream>>>(counts, row_ptr, partial, N);
    k_scan2<<<1, 64, 0, stream>>>(partial, G);
    k_scan3<<<G, 1024, 0, stream>>>(row_ptr, partial, N, Et);
    k_dinv<<<(N + BS - 1) / BS, BS, 0, stream>>>(counts, dinv, N);
    k_fill<<<(Et + BS - 1) / BS, BS, 0, stream>>>(src, dst, row_ptr, cursor, col, E, N);
    k_embed<<<((long)N * 16 + BS - 1) / BS, BS, 0, stream>>>(x, emb, hA16, N);

    const int AGG_BLOCKS = 2048;
    const int NWAVES = AGG_BLOCKS * 4;

    // layer 0
    k_agg<<<AGG_BLOCKS, BS, 0, stream>>>(hA16, row_ptr, col, dinv, hB16, N, NWAVES);
    k_gemm<false><<<(N + 63) / 64, BS, 0, stream>>>(hB16, W0, b0, hA16, nullptr, nullptr, nullptr, N);
    // layer 1 + fused classifier
    k_agg<<<AGG_BLOCKS, BS, 0, stream>>>(hA16, row_ptr, col, dinv, hB16, N, NWAVES);
    k_gemm<true><<<(N + 63) / 64, BS, 0, stream>>>(hB16, W1, b1, nullptr, Wc, bc, out, N);
}

// Round 5
// 225.592 us; speedup vs baseline: 2.3692x; 1.2774x over previous
//
#include <hip/hip_runtime.h>
#include <hip/hip_bf16.h>

#define D 128
#define C 16

typedef unsigned int uint;
typedef unsigned short ushort;
typedef __attribute__((ext_vector_type(8))) short short8;
typedef __attribute__((ext_vector_type(4))) float f32x4;

// RNE pack of two fp32 -> bf16x2 in a uint (lo = a, hi = b)
__device__ __forceinline__ uint pack_bf16(float a, float b) {
    uint ua = __float_as_uint(a);
    uint ub = __float_as_uint(b);
    ua += 0x7fffu + ((ua >> 16) & 1u);
    ub += 0x7fffu + ((ub >> 16) & 1u);
    return (ua >> 16) | (ub & 0xffff0000u);
}
__device__ __forceinline__ ushort bf1(float a) {
    uint u = __float_as_uint(a);
    u += 0x7fffu + ((u >> 16) & 1u);
    return (ushort)(u >> 16);
}
__device__ __forceinline__ float bf_lo(uint u) { return __uint_as_float(u << 16); }
__device__ __forceinline__ float bf_hi(uint u) { return __uint_as_float(u & 0xffff0000u); }

// ---------------------------------------------------------------- setup kernels

__global__ void k_init(int* counts, int* cursor, int N) {
    int i = blockIdx.x * blockDim.x + threadIdx.x;
    if (i < N) { counts[i] = 1; cursor[i] = 0; }   // self-loop counted
}

__global__ void k_hist(const int* __restrict__ dst, int* counts, int E) {
    int e = blockIdx.x * blockDim.x + threadIdx.x;
    if (e < E) atomicAdd(&counts[dst[e]], 1);
}

// ---- 3-kernel parallel exclusive scan: counts -> row_ptr ----
__global__ __launch_bounds__(1024) void k_scan1(const int* __restrict__ counts,
                                                int* row_ptr, int* partial, int N) {
    __shared__ int lds[1024];
    int tid = threadIdx.x;
    int i = blockIdx.x * 1024 + tid;
    int v = (i < N) ? counts[i] : 0;
    lds[tid] = v;
    __syncthreads();
    for (int off = 1; off < 1024; off <<= 1) {
        int t = (tid >= off) ? lds[tid - off] : 0;
        __syncthreads();
        lds[tid] += t;
        __syncthreads();
    }
    int incl = lds[tid];
    if (i < N) row_ptr[i] = incl - v;           // block-local exclusive
    if (tid == 1023) partial[blockIdx.x] = incl;
}

__global__ void k_scan2(int* partial, int G) {
    int lane = threadIdx.x & 63;
    int v = (lane < G) ? partial[lane] : 0;
    int orig = v;
    #pragma unroll
    for (int d = 1; d < 64; d <<= 1) {
        int t = __shfl_up(v, d);
        if (lane >= d) v += t;
    }
    if (lane < G) partial[lane] = v - orig;     // exclusive
}

__global__ __launch_bounds__(1024) void k_scan3(int* row_ptr, const int* __restrict__ partial,
                                                int N, int Et) {
    int i = blockIdx.x * 1024 + threadIdx.x;
    if (i < N) row_ptr[i] += partial[blockIdx.x];
    if (i == 0) row_ptr[N] = Et;
}

__global__ void k_dinv(const int* __restrict__ counts, float* dinv, int N) {
    int i = blockIdx.x * blockDim.x + threadIdx.x;
    if (i < N) {
        float d = (float)counts[i];
        dinv[i] = (d > 0.f) ? rsqrtf(d) : 0.f;
    }
}

__global__ void k_fill(const int* __restrict__ src, const int* __restrict__ dst,
                       const int* __restrict__ row_ptr, int* cursor, int* col,
                       int E, int N) {
    int e = blockIdx.x * blockDim.x + threadIdx.x;
    int Et = E + N;
    if (e >= Et) return;
    int s, d;
    if (e < E) { s = src[e]; d = dst[e]; }
    else       { s = d = e - E; }                  // self-loop
    int pos = row_ptr[d] + atomicAdd(&cursor[d], 1);
    col[pos] = s;
}

// h16[i][:] = bf16(emb[x[i]][:]) ; thread handles 8 values
__global__ void k_embed(const int* __restrict__ x, const float* __restrict__ emb,
                        uint* __restrict__ h16, int N) {
    long idx = (long)blockIdx.x * blockDim.x + threadIdx.x;   // over N*16
    if (idx >= (long)N * 16) return;
    int row = (int)(idx >> 4);
    int j8  = (int)(idx & 15);
    int xr  = x[row];
    const float4* e4 = (const float4*)(emb + (size_t)xr * D + j8 * 8);
    float4 a = e4[0], b = e4[1];
    uint4 o;
    o.x = pack_bf16(a.x, a.y);
    o.y = pack_bf16(a.z, a.w);
    o.z = pack_bf16(b.x, b.y);
    o.w = pack_bf16(b.z, b.w);
    ((uint4*)(h16 + (size_t)row * 64))[j8] = o;
}

// W (fp32 [K][N] row-major) -> Wt (bf16 [N][K], i.e. transposed); Wc -> Wct [C][K]
__global__ void k_wconv(const float* __restrict__ W0, const float* __restrict__ W1,
                        const float* __restrict__ Wc,
                        ushort* __restrict__ Wt0, ushort* __restrict__ Wt1,
                        ushort* __restrict__ Wct) {
    int i = blockIdx.x * 256 + threadIdx.x;
    if (i < D * D) {
        int n = i >> 7, k = i & 127;
        Wt0[i] = bf1(W0[k * D + n]);
        Wt1[i] = bf1(W1[k * D + n]);
    }
    if (i < D * C) {
        int c = i >> 7, k = i & 127;
        Wct[i] = bf1(Wc[k * C + c]);
    }
}

// ---------------------------------------------------------------- aggregation
// persistent waves; bf16 h table (12.8 MB); 8 gathers in flight; fp32 accumulate
__global__ __launch_bounds__(256) void k_agg(const uint* __restrict__ h16,
                                             const int* __restrict__ row_ptr,
                                             const int* __restrict__ col,
                                             const float* __restrict__ dinv,
                                             uint* __restrict__ out16, int N, int nwaves) {
    int gwave = (int)((blockIdx.x * 256u + threadIdx.x) >> 6);
    int lane = threadIdx.x & 63;

    for (int v = gwave; v < N; v += nwaves) {
        int s0 = __builtin_amdgcn_readfirstlane(row_ptr[v]);
        int s1 = __builtin_amdgcn_readfirstlane(row_ptr[v + 1]);
        float dv = dinv[v];
        float ax = 0.f, ay = 0.f;
        int e = s0;
        for (; e + 8 <= s1; e += 8) {
            int c[8]; uint u[8]; float n[8];
            #pragma unroll
            for (int t = 0; t < 8; ++t) c[t] = __builtin_amdgcn_readfirstlane(col[e + t]);
            #pragma unroll
            for (int t = 0; t < 8; ++t) u[t] = h16[(size_t)c[t] * 64 + lane];
            #pragma unroll
            for (int t = 0; t < 8; ++t) n[t] = dinv[c[t]] * dv;
            #pragma unroll
            for (int t = 0; t < 8; ++t) {
                ax = fmaf(bf_lo(u[t]), n[t], ax);
                ay = fmaf(bf_hi(u[t]), n[t], ay);
            }
        }
        for (; e < s1; ++e) {
            int c = __builtin_amdgcn_readfirstlane(col[e]);
            float n = dinv[c] * dv;
            uint u = h16[(size_t)c * 64 + lane];
            ax = fmaf(bf_lo(u), n, ax);
            ay = fmaf(bf_hi(u), n, ay);
        }
        out16[(size_t)v * 64 + lane] = pack_bf16(ax, ay);
    }
}

// ---------------------------------------------------------------- MFMA GEMM
// 4 waves/block, each wave computes a 16-row x 128-col tile of relu(h @ W + b).
// A-frags direct from bf16 h rows; B-frags from Wt (bf16, transposed, L1-hot).
// FUSE=false: bf16 output via LDS transpose, coalesced dwordx4 stores.
// FUSE=true : tile -> LDS (bf16), second MFMA pass vs Wct -> fp32 logits.
template<bool FUSE>
__global__ __launch_bounds__(256) void k_gemm_mfma(const uint* __restrict__ hin,     // bf16x2 [N][64]
                                                   const ushort* __restrict__ Wt,    // bf16 [128][128] (n-major)
                                                   const float* __restrict__ b,
                                                   uint* __restrict__ hout16,
                                                   const ushort* __restrict__ Wct,   // bf16 [16][128]
                                                   const float* __restrict__ bc,
                                                   float* __restrict__ outf, int N) {
    __shared__ __align__(16) ushort T[64][136];    // +8 pad: conflict-free b128 reads
    int tid  = threadIdx.x;
    int lane = tid & 63, wv = tid >> 6;
    int c0 = lane & 15, g = lane >> 4;             // A-row / D-col = c0 ; k/row group = g
    long wrow = (long)blockIdx.x * 64 + wv * 16;
    long arow = wrow + c0; if (arow >= N) arow = N - 1;

    // A-fragments: lane holds h[arow][kk*32 + g*8 .. +8]
    short8 a[4];
    const uint* hr = hin + (size_t)arow * 64;
    #pragma unroll
    for (int kk = 0; kk < 4; ++kk)
        a[kk] = *(const short8*)(hr + kk * 16 + g * 4);

    #pragma unroll
    for (int nt = 0; nt < 8; ++nt) {
        float bias = b[nt * 16 + c0];
        f32x4 acc = {bias, bias, bias, bias};
        const ushort* wb = Wt + (size_t)(nt * 16 + c0) * D + g * 8;
        #pragma unroll
        for (int kk = 0; kk < 4; ++kk) {
            short8 bf = *(const short8*)(wb + kk * 32);
            acc = __builtin_amdgcn_mfma_f32_16x16x32_bf16(a[kk], bf, acc, 0, 0, 0);
        }
        // D: row = 4*g + j, col = nt*16 + c0 ; relu + bf16 -> LDS
        #pragma unroll
        for (int j = 0; j < 4; ++j)
            T[wv * 16 + g * 4 + j][nt * 16 + c0] = bf1(fmaxf(acc[j], 0.f));
    }
    __syncthreads();

    if (!FUSE) {
        // coalesced store: thread t writes 64 B of row (t>>2)
        int r = tid >> 2, q = tid & 3;
        long grow = (long)blockIdx.x * 64 + r;
        if (grow < N) {
            uint4* dstp = (uint4*)(hout16 + grow * 64 + q * 16);
            const uint4* srcp = (const uint4*)((const char*)&T[r][0] + q * 64);
            #pragma unroll
            for (int i = 0; i < 4; ++i) dstp[i] = srcp[i];
        }
    } else {
        // classifier: out[row][c0] = T[row][:] @ Wct[c0][:] + bc[c0]
        float biasc = bc[c0];
        f32x4 acc2 = {biasc, biasc, biasc, biasc};
        #pragma unroll
        for (int kk = 0; kk < 4; ++kk) {
            short8 ta = *(const short8*)((const char*)&T[wv * 16 + c0][0] + kk * 64 + g * 16);
            short8 wc = *(const short8*)(Wct + (size_t)c0 * D + kk * 32 + g * 8);
            acc2 = __builtin_amdgcn_mfma_f32_16x16x32_bf16(ta, wc, acc2, 0, 0, 0);
        }
        #pragma unroll
        for (int j = 0; j < 4; ++j) {
            long grow = wrow + g * 4 + j;
            if (grow < N) outf[grow * C + c0] = acc2[j];
        }
    }
}

// ---------------------------------------------------------------- launch

extern "C" void kernel_launch(void* const* d_in, const int* in_sizes, int n_in,
                              void* d_out, int out_size, void* d_ws, size_t ws_size,
                              hipStream_t stream) {
    const int*   x    = (const int*)  d_in[0];
    const int*   ei   = (const int*)  d_in[1];   // [2,E]: first E = src, next E = dst
    const float* emb  = (const float*)d_in[2];
    const float* W0   = (const float*)d_in[3];
    const float* b0   = (const float*)d_in[4];
    const float* W1   = (const float*)d_in[5];
    const float* b1   = (const float*)d_in[6];
    const float* Wc   = (const float*)d_in[7];
    const float* bc   = (const float*)d_in[8];
    float* out = (float*)d_out;

    const int N  = in_sizes[0];
    const int E  = in_sizes[1] / 2;
    const int Et = E + N;

    const int* src = ei;
    const int* dst = ei + E;

    char* p = (char*)d_ws;
    auto take = [&](size_t bytes) { char* q = p; p += (bytes + 255) & ~(size_t)255; return q; };
    int*    counts  = (int*)   take((size_t)N * 4);
    int*    cursor  = (int*)   take((size_t)N * 4);
    int*    row_ptr = (int*)   take((size_t)(N + 1) * 4);
    float*  dinv    = (float*) take((size_t)N * 4);
    int*    partial = (int*)   take((size_t)1024 * 4);
    int*    col     = (int*)   take((size_t)Et * 4);
    ushort* Wt0     = (ushort*)take((size_t)D * D * 2);
    ushort* Wt1     = (ushort*)take((size_t)D * D * 2);
    ushort* Wct     = (ushort*)take((size_t)D * C * 2);
    uint*   hA16    = (uint*)  take((size_t)N * 64 * 4);   // bf16 h table A
    uint*   hB16    = (uint*)  take((size_t)N * 64 * 4);   // bf16 h table B

    const int BS = 256;
    const int G  = (N + 1023) / 1024;

    k_init<<<(N + BS - 1) / BS, BS, 0, stream>>>(counts, cursor, N);
    k_hist<<<(E + BS - 1) / BS, BS, 0, stream>>>(dst, counts, E);
    k_scan1<<<G, 1024, 0, stream>>>(counts, row_ptr, partial, N);
    k_scan2<<<1, 64, 0, stream>>>(partial, G);
    k_scan3<<<G, 1024, 0, stream>>>(row_ptr, partial, N, Et);
    k_dinv<<<(N + BS - 1) / BS, BS, 0, stream>>>(counts, dinv, N);
    k_fill<<<(Et + BS - 1) / BS, BS, 0, stream>>>(src, dst, row_ptr, cursor, col, E, N);
    k_embed<<<((long)N * 16 + BS - 1) / BS, BS, 0, stream>>>(x, emb, hA16, N);
    k_wconv<<<(D * D + 255) / 256, 256, 0, stream>>>(W0, W1, Wc, Wt0, Wt1, Wct);

    const int AGG_BLOCKS = 2048;
    const int NWAVES = AGG_BLOCKS * 4;
    const int GEMM_BLOCKS = (N + 63) / 64;

    // layer 0
    k_agg<<<AGG_BLOCKS, BS, 0, stream>>>(hA16, row_ptr, col, dinv, hB16, N, NWAVES);
    k_gemm_mfma<false><<<GEMM_BLOCKS, BS, 0, stream>>>(hB16, Wt0, b0, hA16, nullptr, nullptr, nullptr, N);
    // layer 1 + fused classifier
    k_agg<<<AGG_BLOCKS, BS, 0, stream>>>(hA16, row_ptr, col, dinv, hB16, N, NWAVES);
    k_gemm_mfma<true><<<GEMM_BLOCKS, BS, 0, stream>>>(hB16, Wt1, b1, nullptr, Wct, bc, out, N);
}

// Round 6
// 188.289 us; speedup vs baseline: 2.8385x; 1.1981x over previous
//
#include <hip/hip_runtime.h>
#include <hip/hip_bf16.h>

#define D 128
#define C 16
#define NBMAX 512     // max buckets
#define VPT 16        // edges per thread in bucket passes

typedef unsigned int uint;
typedef unsigned short ushort;
typedef __attribute__((ext_vector_type(8))) short short8;
typedef __attribute__((ext_vector_type(4))) float f32x4;

// RNE pack of two fp32 -> bf16x2 in a uint (lo = a, hi = b)
__device__ __forceinline__ uint pack_bf16(float a, float b) {
    uint ua = __float_as_uint(a);
    uint ub = __float_as_uint(b);
    ua += 0x7fffu + ((ua >> 16) & 1u);
    ub += 0x7fffu + ((ub >> 16) & 1u);
    return (ua >> 16) | (ub & 0xffff0000u);
}
__device__ __forceinline__ ushort bf1(float a) {
    uint u = __float_as_uint(a);
    u += 0x7fffu + ((u >> 16) & 1u);
    return (ushort)(u >> 16);
}
__device__ __forceinline__ float bf_lo(uint u) { return __uint_as_float(u << 16); }
__device__ __forceinline__ float bf_hi(uint u) { return __uint_as_float(u & 0xffff0000u); }

// ---------------------------------------------------------------- bucket sort
// pass 1: bucket histogram (LDS-privatized)
__global__ __launch_bounds__(256) void k_bhist(const int* __restrict__ dst,
                                               int* __restrict__ bcnt, int E, int shift) {
    __shared__ int lc[NBMAX];
    int tid = threadIdx.x;
    lc[tid] = 0; lc[tid + 256] = 0;
    __syncthreads();
    long e0 = (long)blockIdx.x * (256 * VPT);
    #pragma unroll
    for (int t = 0; t < VPT; ++t) {
        long e = e0 + t * 256 + tid;
        if (e < E) atomicAdd(&lc[dst[e] >> shift], 1);
    }
    __syncthreads();
    for (int b = tid; b < NBMAX; b += 256)
        if (lc[b]) atomicAdd(&bcnt[b], lc[b]);
}

// pass 2: single-block scan of bucket counts -> base & cursor
__global__ __launch_bounds__(NBMAX) void k_bscan(const int* __restrict__ bcnt,
                                                 int* __restrict__ bbase,
                                                 int* __restrict__ bcur, int NB) {
    __shared__ int lds[NBMAX];
    int tid = threadIdx.x;
    int v = (tid < NB) ? bcnt[tid] : 0;
    lds[tid] = v;
    __syncthreads();
    for (int off = 1; off < NBMAX; off <<= 1) {
        int t = (tid >= off) ? lds[tid - off] : 0;
        __syncthreads();
        lds[tid] += t;
        __syncthreads();
    }
    int excl = lds[tid] - v;
    if (tid < NB) { bbase[tid] = excl; bcur[tid] = excl; }
    if (tid == NBMAX - 1) bbase[NB] = lds[NBMAX - 1];
}

// pass 3: scatter edges into bucket-ordered tmp, packed src | dstoff<<17
__global__ __launch_bounds__(256) void k_bscatter(const int* __restrict__ src,
                                                  const int* __restrict__ dst,
                                                  int* __restrict__ bcur,
                                                  uint* __restrict__ tmp,
                                                  int E, int shift) {
    __shared__ int lcnt[NBMAX];
    __shared__ int lbase[NBMAX];
    int tid = threadIdx.x;
    int mask = (1 << shift) - 1;
    lcnt[tid] = 0; lcnt[tid + 256] = 0;
    __syncthreads();
    long e0 = (long)blockIdx.x * (256 * VPT);
    uint ps[VPT]; int pb[VPT];
    #pragma unroll
    for (int t = 0; t < VPT; ++t) {
        long e = e0 + t * 256 + tid;
        if (e < E) {
            int s = src[e], d = dst[e];
            int b = d >> shift;
            pb[t] = b;
            ps[t] = (uint)s | ((uint)(d & mask) << 17);
            atomicAdd(&lcnt[b], 1);
        } else pb[t] = -1;
    }
    __syncthreads();
    for (int b = tid; b < NBMAX; b += 256) {
        int c = lcnt[b];
        lbase[b] = c ? atomicAdd(&bcur[b], c) : 0;
    }
    __syncthreads();
    lcnt[tid] = 0; lcnt[tid + 256] = 0;
    __syncthreads();
    #pragma unroll
    for (int t = 0; t < VPT; ++t) {
        if (pb[t] >= 0) {
            int r = atomicAdd(&lcnt[pb[t]], 1);
            tmp[lbase[pb[t]] + r] = ps[t];
        }
    }
}

// pass 4: per-bucket node degrees via LDS counters (no global atomics); zero cursor
__global__ __launch_bounds__(256) void k_count(const uint* __restrict__ tmp,
                                               const int* __restrict__ bbase,
                                               int* __restrict__ counts,
                                               int* __restrict__ cursor,
                                               int N, int shift) {
    __shared__ int lc[NBMAX];
    int b = blockIdx.x, tid = threadIdx.x;
    int W = 1 << shift;
    for (int i = tid; i < W; i += 256) lc[i] = 0;
    __syncthreads();
    int s0 = bbase[b], s1 = bbase[b + 1];
    for (int i = s0 + tid; i < s1; i += 256)
        atomicAdd(&lc[tmp[i] >> 17], 1);
    __syncthreads();
    for (int i = tid; i < W; i += 256) {
        int v = (b << shift) + i;
        if (v < N) { counts[v] = lc[i] + 1; cursor[v] = 0; }   // +1 self-loop
    }
}

// pass 5: CSR fill from bucket-sorted tmp; atomics/writes confined per bucket
__global__ __launch_bounds__(256) void k_fill2(const uint* __restrict__ tmp,
                                               const int* __restrict__ bbase,
                                               const int* __restrict__ row_ptr,
                                               int* __restrict__ cursor,
                                               int* __restrict__ col,
                                               int N, int shift) {
    int b = blockIdx.x, tid = threadIdx.x;
    int W = 1 << shift;
    // self-loops for this bucket's nodes
    for (int i = tid; i < W; i += 256) {
        int v = (b << shift) + i;
        if (v < N) {
            int pos = row_ptr[v] + atomicAdd(&cursor[v], 1);
            col[pos] = v;
        }
    }
    int s0 = bbase[b], s1 = bbase[b + 1];
    for (int i = s0 + tid; i < s1; i += 256) {
        uint u = tmp[i];
        int s = (int)(u & 0x1FFFFu);
        int v = (b << shift) + (int)(u >> 17);
        int pos = row_ptr[v] + atomicAdd(&cursor[v], 1);
        col[pos] = s;
    }
}

// ---- 3-kernel parallel exclusive scan: counts -> row_ptr ----
__global__ __launch_bounds__(1024) void k_scan1(const int* __restrict__ counts,
                                                int* row_ptr, int* partial, int N) {
    __shared__ int lds[1024];
    int tid = threadIdx.x;
    int i = blockIdx.x * 1024 + tid;
    int v = (i < N) ? counts[i] : 0;
    lds[tid] = v;
    __syncthreads();
    for (int off = 1; off < 1024; off <<= 1) {
        int t = (tid >= off) ? lds[tid - off] : 0;
        __syncthreads();
        lds[tid] += t;
        __syncthreads();
    }
    int incl = lds[tid];
    if (i < N) row_ptr[i] = incl - v;           // block-local exclusive
    if (tid == 1023) partial[blockIdx.x] = incl;
}

__global__ void k_scan2(int* partial, int G) {
    int lane = threadIdx.x & 63;
    int v = (lane < G) ? partial[lane] : 0;
    int orig = v;
    #pragma unroll
    for (int d = 1; d < 64; d <<= 1) {
        int t = __shfl_up(v, d);
        if (lane >= d) v += t;
    }
    if (lane < G) partial[lane] = v - orig;     // exclusive
}

__global__ __launch_bounds__(1024) void k_scan3(int* row_ptr, const int* __restrict__ partial,
                                                int N, int Et) {
    int i = blockIdx.x * 1024 + threadIdx.x;
    if (i < N) row_ptr[i] += partial[blockIdx.x];
    if (i == 0) row_ptr[N] = Et;
}

__global__ void k_dinv(const int* __restrict__ counts, float* dinv, int N) {
    int i = blockIdx.x * blockDim.x + threadIdx.x;
    if (i < N) {
        float d = (float)counts[i];
        dinv[i] = (d > 0.f) ? rsqrtf(d) : 0.f;
    }
}

// h16[i][:] = bf16(emb[x[i]][:]) ; thread handles 8 values
__global__ void k_embed(const int* __restrict__ x, const float* __restrict__ emb,
                        uint* __restrict__ h16, int N) {
    long idx = (long)blockIdx.x * blockDim.x + threadIdx.x;   // over N*16
    if (idx >= (long)N * 16) return;
    int row = (int)(idx >> 4);
    int j8  = (int)(idx & 15);
    int xr  = x[row];
    const float4* e4 = (const float4*)(emb + (size_t)xr * D + j8 * 8);
    float4 a = e4[0], b = e4[1];
    uint4 o;
    o.x = pack_bf16(a.x, a.y);
    o.y = pack_bf16(a.z, a.w);
    o.z = pack_bf16(b.x, b.y);
    o.w = pack_bf16(b.z, b.w);
    ((uint4*)(h16 + (size_t)row * 64))[j8] = o;
}

// W (fp32 [K][N] row-major) -> Wt (bf16 [N][K], transposed); Wc -> Wct [C][K]
__global__ void k_wconv(const float* __restrict__ W0, const float* __restrict__ W1,
                        const float* __restrict__ Wc,
                        ushort* __restrict__ Wt0, ushort* __restrict__ Wt1,
                        ushort* __restrict__ Wct) {
    int i = blockIdx.x * 256 + threadIdx.x;
    if (i < D * D) {
        int n = i >> 7, k = i & 127;
        Wt0[i] = bf1(W0[k * D + n]);
        Wt1[i] = bf1(W1[k * D + n]);
    }
    if (i < D * C) {
        int c = i >> 7, k = i & 127;
        Wct[i] = bf1(Wc[k * C + c]);
    }
}

// ---------------------------------------------------------------- aggregation
// persistent waves; bf16 h table (12.8 MB); 8 gathers in flight; fp32 accumulate
__global__ __launch_bounds__(256) void k_agg(const uint* __restrict__ h16,
                                             const int* __restrict__ row_ptr,
                                             const int* __restrict__ col,
                                             const float* __restrict__ dinv,
                                             uint* __restrict__ out16, int N, int nwaves) {
    int gwave = (int)((blockIdx.x * 256u + threadIdx.x) >> 6);
    int lane = threadIdx.x & 63;

    for (int v = gwave; v < N; v += nwaves) {
        int s0 = __builtin_amdgcn_readfirstlane(row_ptr[v]);
        int s1 = __builtin_amdgcn_readfirstlane(row_ptr[v + 1]);
        float dv = dinv[v];
        float ax = 0.f, ay = 0.f;
        int e = s0;
        for (; e + 8 <= s1; e += 8) {
            int c[8]; uint u[8]; float n[8];
            #pragma unroll
            for (int t = 0; t < 8; ++t) c[t] = __builtin_amdgcn_readfirstlane(col[e + t]);
            #pragma unroll
            for (int t = 0; t < 8; ++t) u[t] = h16[(size_t)c[t] * 64 + lane];
            #pragma unroll
            for (int t = 0; t < 8; ++t) n[t] = dinv[c[t]] * dv;
            #pragma unroll
            for (int t = 0; t < 8; ++t) {
                ax = fmaf(bf_lo(u[t]), n[t], ax);
                ay = fmaf(bf_hi(u[t]), n[t], ay);
            }
        }
        for (; e < s1; ++e) {
            int c = __builtin_amdgcn_readfirstlane(col[e]);
            float n = dinv[c] * dv;
            uint u = h16[(size_t)c * 64 + lane];
            ax = fmaf(bf_lo(u), n, ax);
            ay = fmaf(bf_hi(u), n, ay);
        }
        out16[(size_t)v * 64 + lane] = pack_bf16(ax, ay);
    }
}

// ---------------------------------------------------------------- MFMA GEMM
// 4 waves/block, each wave: 16-row x 128-col tile of relu(h @ W + b).
template<bool FUSE>
__global__ __launch_bounds__(256) void k_gemm_mfma(const uint* __restrict__ hin,     // bf16x2 [N][64]
                                                   const ushort* __restrict__ Wt,    // bf16 [128][128] (n-major)
                                                   const float* __restrict__ b,
                                                   uint* __restrict__ hout16,
                                                   const ushort* __restrict__ Wct,   // bf16 [16][128]
                                                   const float* __restrict__ bc,
                                                   float* __restrict__ outf, int N) {
    __shared__ __align__(16) ushort T[64][136];    // +8 pad: conflict-free b128 reads
    int tid  = threadIdx.x;
    int lane = tid & 63, wv = tid >> 6;
    int c0 = lane & 15, g = lane >> 4;
    long wrow = (long)blockIdx.x * 64 + wv * 16;
    long arow = wrow + c0; if (arow >= N) arow = N - 1;

    short8 a[4];
    const uint* hr = hin + (size_t)arow * 64;
    #pragma unroll
    for (int kk = 0; kk < 4; ++kk)
        a[kk] = *(const short8*)(hr + kk * 16 + g * 4);

    #pragma unroll
    for (int nt = 0; nt < 8; ++nt) {
        float bias = b[nt * 16 + c0];
        f32x4 acc = {bias, bias, bias, bias};
        const ushort* wb = Wt + (size_t)(nt * 16 + c0) * D + g * 8;
        #pragma unroll
        for (int kk = 0; kk < 4; ++kk) {
            short8 bf = *(const short8*)(wb + kk * 32);
            acc = __builtin_amdgcn_mfma_f32_16x16x32_bf16(a[kk], bf, acc, 0, 0, 0);
        }
        #pragma unroll
        for (int j = 0; j < 4; ++j)
            T[wv * 16 + g * 4 + j][nt * 16 + c0] = bf1(fmaxf(acc[j], 0.f));
    }
    __syncthreads();

    if (!FUSE) {
        int r = tid >> 2, q = tid & 3;
        long grow = (long)blockIdx.x * 64 + r;
        if (grow < N) {
            uint4* dstp = (uint4*)(hout16 + grow * 64 + q * 16);
            const uint4* srcp = (const uint4*)((const char*)&T[r][0] + q * 64);
            #pragma unroll
            for (int i = 0; i < 4; ++i) dstp[i] = srcp[i];
        }
    } else {
        float biasc = bc[c0];
        f32x4 acc2 = {biasc, biasc, biasc, biasc};
        #pragma unroll
        for (int kk = 0; kk < 4; ++kk) {
            short8 ta = *(const short8*)((const char*)&T[wv * 16 + c0][0] + kk * 64 + g * 16);
            short8 wc = *(const short8*)(Wct + (size_t)c0 * D + kk * 32 + g * 8);
            acc2 = __builtin_amdgcn_mfma_f32_16x16x32_bf16(ta, wc, acc2, 0, 0, 0);
        }
        #pragma unroll
        for (int j = 0; j < 4; ++j) {
            long grow = wrow + g * 4 + j;
            if (grow < N) outf[grow * C + c0] = acc2[j];
        }
    }
}

// ---------------------------------------------------------------- launch

extern "C" void kernel_launch(void* const* d_in, const int* in_sizes, int n_in,
                              void* d_out, int out_size, void* d_ws, size_t ws_size,
                              hipStream_t stream) {
    const int*   x    = (const int*)  d_in[0];
    const int*   ei   = (const int*)  d_in[1];   // [2,E]: first E = src, next E = dst
    const float* emb  = (const float*)d_in[2];
    const float* W0   = (const float*)d_in[3];
    const float* b0   = (const float*)d_in[4];
    const float* W1   = (const float*)d_in[5];
    const float* b1   = (const float*)d_in[6];
    const float* Wc   = (const float*)d_in[7];
    const float* bc   = (const float*)d_in[8];
    float* out = (float*)d_out;

    const int N  = in_sizes[0];
    const int E  = in_sizes[1] / 2;
    const int Et = E + N;

    const int* src = ei;
    const int* dst = ei + E;

    // bucket shift: width 2^shift, NB <= NBMAX  (N=50000 -> shift 7, NB=391)
    int shift = 7;
    while (((N + (1 << shift) - 1) >> shift) > NBMAX) shift++;
    const int NB = (N + (1 << shift) - 1) >> shift;

    char* p = (char*)d_ws;
    auto take = [&](size_t bytes) { char* q = p; p += (bytes + 255) & ~(size_t)255; return q; };
    int*    counts  = (int*)   take((size_t)N * 4);
    int*    cursor  = (int*)   take((size_t)N * 4);
    int*    row_ptr = (int*)   take((size_t)(N + 1) * 4);
    float*  dinv    = (float*) take((size_t)N * 4);
    int*    partial = (int*)   take((size_t)1024 * 4);
    int*    bcnt    = (int*)   take((size_t)NBMAX * 4);
    int*    bbase   = (int*)   take((size_t)(NBMAX + 1) * 4);
    int*    bcur    = (int*)   take((size_t)NBMAX * 4);
    uint*   tmp     = (uint*)  take((size_t)E * 4);
    int*    col     = (int*)   take((size_t)Et * 4);
    ushort* Wt0     = (ushort*)take((size_t)D * D * 2);
    ushort* Wt1     = (ushort*)take((size_t)D * D * 2);
    ushort* Wct     = (ushort*)take((size_t)D * C * 2);
    uint*   hA16    = (uint*)  take((size_t)N * 64 * 4);
    uint*   hB16    = (uint*)  take((size_t)N * 64 * 4);

    const int BS = 256;
    const int G  = (N + 1023) / 1024;
    const int EB = (int)(((long)E + 256 * VPT - 1) / (256 * VPT));

    hipMemsetAsync(bcnt, 0, NBMAX * 4, stream);
    k_bhist   <<<EB, BS, 0, stream>>>(dst, bcnt, E, shift);
    k_bscan   <<<1, NBMAX, 0, stream>>>(bcnt, bbase, bcur, NB);
    k_bscatter<<<EB, BS, 0, stream>>>(src, dst, bcur, tmp, E, shift);
    k_count   <<<NB, BS, 0, stream>>>(tmp, bbase, counts, cursor, N, shift);
    k_scan1   <<<G, 1024, 0, stream>>>(counts, row_ptr, partial, N);
    k_scan2   <<<1, 64, 0, stream>>>(partial, G);
    k_scan3   <<<G, 1024, 0, stream>>>(row_ptr, partial, N, Et);
    k_dinv    <<<(N + BS - 1) / BS, BS, 0, stream>>>(counts, dinv, N);
    k_fill2   <<<NB, BS, 0, stream>>>(tmp, bbase, row_ptr, cursor, col, N, shift);
    k_embed   <<<((long)N * 16 + BS - 1) / BS, BS, 0, stream>>>(x, emb, hA16, N);
    k_wconv   <<<(D * D + 255) / 256, 256, 0, stream>>>(W0, W1, Wc, Wt0, Wt1, Wct);

    const int AGG_BLOCKS = 2048;
    const int NWAVES = AGG_BLOCKS * 4;
    const int GEMM_BLOCKS = (N + 63) / 64;

    // layer 0
    k_agg<<<AGG_BLOCKS, BS, 0, stream>>>(hA16, row_ptr, col, dinv, hB16, N, NWAVES);
    k_gemm_mfma<false><<<GEMM_BLOCKS, BS, 0, stream>>>(hB16, Wt0, b0, hA16, nullptr, nullptr, nullptr, N);
    // layer 1 + fused classifier
    k_agg<<<AGG_BLOCKS, BS, 0, stream>>>(hA16, row_ptr, col, dinv, hB16, N, NWAVES);
    k_gemm_mfma<true><<<GEMM_BLOCKS, BS, 0, stream>>>(hB16, Wt1, b1, nullptr, Wct, bc, out, N);
}

// Round 7
// 161.618 us; speedup vs baseline: 3.3070x; 1.1650x over previous
//
#include <hip/hip_runtime.h>
#include <hip/hip_bf16.h>

#define D 128
#define C 16
#define NBMAX 512     // max buckets
#define VPT 16        // edges per thread in bucket passes

typedef unsigned int uint;
typedef unsigned short ushort;
typedef __attribute__((ext_vector_type(8))) short short8;
typedef __attribute__((ext_vector_type(4))) float f32x4;

// RNE pack of two fp32 -> bf16x2 in a uint (lo = a, hi = b)
__device__ __forceinline__ uint pack_bf16(float a, float b) {
    uint ua = __float_as_uint(a);
    uint ub = __float_as_uint(b);
    ua += 0x7fffu + ((ua >> 16) & 1u);
    ub += 0x7fffu + ((ub >> 16) & 1u);
    return (ua >> 16) | (ub & 0xffff0000u);
}
__device__ __forceinline__ ushort bf1(float a) {
    uint u = __float_as_uint(a);
    u += 0x7fffu + ((u >> 16) & 1u);
    return (ushort)(u >> 16);
}
__device__ __forceinline__ float bf_lo(uint u) { return __uint_as_float(u << 16); }
__device__ __forceinline__ float bf_hi(uint u) { return __uint_as_float(u & 0xffff0000u); }

// ---------------------------------------------------------------- bucket sort
// pass 1: bucket histogram (LDS-privatized)
__global__ __launch_bounds__(256) void k_bhist(const int* __restrict__ dst,
                                               int* __restrict__ bcnt, int E, int shift) {
    __shared__ int lc[NBMAX];
    int tid = threadIdx.x;
    lc[tid] = 0; lc[tid + 256] = 0;
    __syncthreads();
    long e0 = (long)blockIdx.x * (256 * VPT);
    #pragma unroll
    for (int t = 0; t < VPT; ++t) {
        long e = e0 + t * 256 + tid;
        if (e < E) atomicAdd(&lc[dst[e] >> shift], 1);
    }
    __syncthreads();
    for (int b = tid; b < NBMAX; b += 256)
        if (lc[b]) atomicAdd(&bcnt[b], lc[b]);
}

// pass 2: single-block scan of bucket counts -> base & cursor
__global__ __launch_bounds__(NBMAX) void k_bscan(const int* __restrict__ bcnt,
                                                 int* __restrict__ bbase,
                                                 int* __restrict__ bcur, int NB) {
    __shared__ int lds[NBMAX];
    int tid = threadIdx.x;
    int v = (tid < NB) ? bcnt[tid] : 0;
    lds[tid] = v;
    __syncthreads();
    for (int off = 1; off < NBMAX; off <<= 1) {
        int t = (tid >= off) ? lds[tid - off] : 0;
        __syncthreads();
        lds[tid] += t;
        __syncthreads();
    }
    int excl = lds[tid] - v;
    if (tid < NB) { bbase[tid] = excl; bcur[tid] = excl; }
    if (tid == NBMAX - 1) bbase[NB] = lds[NBMAX - 1];
}

// pass 3: scatter edges into bucket-ordered tmp, packed src | dstoff<<17
__global__ __launch_bounds__(256) void k_bscatter(const int* __restrict__ src,
                                                  const int* __restrict__ dst,
                                                  int* __restrict__ bcur,
                                                  uint* __restrict__ tmp,
                                                  int E, int shift) {
    __shared__ int lcnt[NBMAX];
    __shared__ int lbase[NBMAX];
    int tid = threadIdx.x;
    int mask = (1 << shift) - 1;
    lcnt[tid] = 0; lcnt[tid + 256] = 0;
    __syncthreads();
    long e0 = (long)blockIdx.x * (256 * VPT);
    uint ps[VPT]; int pb[VPT];
    #pragma unroll
    for (int t = 0; t < VPT; ++t) {
        long e = e0 + t * 256 + tid;
        if (e < E) {
            int s = src[e], d = dst[e];
            int b = d >> shift;
            pb[t] = b;
            ps[t] = (uint)s | ((uint)(d & mask) << 17);
            atomicAdd(&lcnt[b], 1);
        } else pb[t] = -1;
    }
    __syncthreads();
    for (int b = tid; b < NBMAX; b += 256) {
        int c = lcnt[b];
        lbase[b] = c ? atomicAdd(&bcur[b], c) : 0;
    }
    __syncthreads();
    lcnt[tid] = 0; lcnt[tid + 256] = 0;
    __syncthreads();
    #pragma unroll
    for (int t = 0; t < VPT; ++t) {
        if (pb[t] >= 0) {
            int r = atomicAdd(&lcnt[pb[t]], 1);
            tmp[lbase[pb[t]] + r] = ps[t];
        }
    }
}

// pass 4 (fused): per-bucket degree count + local row_ptr scan + dinv + CSR fill.
// All cursors live in LDS; no global atomics. row_ptr[v] = bbase[b] + selfloops_before + local_scan.
__global__ __launch_bounds__(256) void k_build(const uint* __restrict__ tmp,
                                               const int* __restrict__ bbase,
                                               int* __restrict__ row_ptr,
                                               float* __restrict__ dinv,
                                               int* __restrict__ col,
                                               int N, int shift, int NB, int Et) {
    __shared__ int lc[256];     // edge degree per node (excl. self-loop)
    __shared__ int lrow[256];   // scan buffer -> global row start
    __shared__ int lcur[256];   // fill cursor
    int b = blockIdx.x, tid = threadIdx.x;
    int W = 1 << shift;         // 128 for this problem
    if (tid < W) lc[tid] = 0;
    __syncthreads();
    int s0 = bbase[b], s1 = bbase[b + 1];
    for (int i = s0 + tid; i < s1; i += 256)
        atomicAdd(&lc[tmp[i] >> 17], 1);
    __syncthreads();
    int v0 = (b << shift) + tid;
    int deg = 0;
    if (tid < W) deg = (v0 < N) ? lc[tid] + 1 : 0;   // +1 self-loop
    if (tid < W) lrow[tid] = deg;
    __syncthreads();
    for (int off = 1; off < W; off <<= 1) {
        int t = 0;
        if (tid < W && tid >= off) t = lrow[tid - off];
        __syncthreads();
        if (tid < W) lrow[tid] += t;
        __syncthreads();
    }
    int base = s0 + min(b << shift, N);   // edges-before + selfloops-before
    if (tid < W) {
        int rstart = base + lrow[tid] - deg;          // exclusive scan
        lrow[tid] = rstart;
        lcur[tid] = 1;                                // slot 0 = self-loop
        if (v0 < N) {
            row_ptr[v0] = rstart;
            dinv[v0] = rsqrtf((float)deg);
            col[rstart] = v0;
        }
    }
    if (b == NB - 1 && tid == 0) row_ptr[N] = Et;
    __syncthreads();
    for (int i = s0 + tid; i < s1; i += 256) {
        uint u = tmp[i];
        int off = (int)(u >> 17);
        int r = atomicAdd(&lcur[off], 1);
        col[lrow[off] + r] = (int)(u & 0x1FFFFu);
    }
}

// h16[i][:] = bf16(emb[x[i]][:] * dinv[i])  (pre-scaled feature table)
__global__ void k_embed(const int* __restrict__ x, const float* __restrict__ emb,
                        const float* __restrict__ dinv,
                        uint* __restrict__ h16, int N) {
    long idx = (long)blockIdx.x * blockDim.x + threadIdx.x;   // over N*16
    if (idx >= (long)N * 16) return;
    int row = (int)(idx >> 4);
    int j8  = (int)(idx & 15);
    int xr  = x[row];
    float dv = dinv[row];
    const float4* e4 = (const float4*)(emb + (size_t)xr * D + j8 * 8);
    float4 a = e4[0], b = e4[1];
    uint4 o;
    o.x = pack_bf16(a.x * dv, a.y * dv);
    o.y = pack_bf16(a.z * dv, a.w * dv);
    o.z = pack_bf16(b.x * dv, b.y * dv);
    o.w = pack_bf16(b.z * dv, b.w * dv);
    ((uint4*)(h16 + (size_t)row * 64))[j8] = o;
}

// W (fp32 [K][N] row-major) -> Wt (bf16 [N][K], transposed); Wc -> Wct [C][K]
__global__ void k_wconv(const float* __restrict__ W0, const float* __restrict__ W1,
                        const float* __restrict__ Wc,
                        ushort* __restrict__ Wt0, ushort* __restrict__ Wt1,
                        ushort* __restrict__ Wct) {
    int i = blockIdx.x * 256 + threadIdx.x;
    if (i < D * D) {
        int n = i >> 7, k = i & 127;
        Wt0[i] = bf1(W0[k * D + n]);
        Wt1[i] = bf1(W1[k * D + n]);
    }
    if (i < D * C) {
        int c = i >> 7, k = i & 127;
        Wct[i] = bf1(Wc[k * C + c]);
    }
}

// ---------------------------------------------------------------- aggregation
// h table pre-scaled by dinv[src]; inner loop = pure row-sum; final *dinv[v].
__global__ __launch_bounds__(256) void k_agg(const uint* __restrict__ h16,
                                             const int* __restrict__ row_ptr,
                                             const int* __restrict__ col,
                                             const float* __restrict__ dinv,
                                             uint* __restrict__ out16, int N, int nwaves) {
    int gwave = (int)((blockIdx.x * 256u + threadIdx.x) >> 6);
    int lane = threadIdx.x & 63;

    for (int v = gwave; v < N; v += nwaves) {
        int s0 = __builtin_amdgcn_readfirstlane(row_ptr[v]);
        int s1 = __builtin_amdgcn_readfirstlane(row_ptr[v + 1]);
        float ax = 0.f, ay = 0.f;
        int e = s0;
        for (; e + 8 <= s1; e += 8) {
            int c[8]; uint u[8];
            #pragma unroll
            for (int t = 0; t < 8; ++t) c[t] = __builtin_amdgcn_readfirstlane(col[e + t]);
            #pragma unroll
            for (int t = 0; t < 8; ++t) u[t] = h16[(size_t)c[t] * 64 + lane];
            #pragma unroll
            for (int t = 0; t < 8; ++t) {
                ax += bf_lo(u[t]);
                ay += bf_hi(u[t]);
            }
        }
        for (; e < s1; ++e) {
            int c = __builtin_amdgcn_readfirstlane(col[e]);
            uint u = h16[(size_t)c * 64 + lane];
            ax += bf_lo(u);
            ay += bf_hi(u);
        }
        float dv = dinv[v];
        out16[(size_t)v * 64 + lane] = pack_bf16(ax * dv, ay * dv);
    }
}

// ---------------------------------------------------------------- MFMA GEMM
// 4 waves/block, each wave: 16-row x 128-col tile of relu(h @ W + b).
// FUSE=false: epilogue pre-scales by dinv[row] (next agg's src factor), bf16 out.
// FUSE=true : tile -> LDS (bf16), second MFMA pass vs Wct -> fp32 logits.
template<bool FUSE>
__global__ __launch_bounds__(256) void k_gemm_mfma(const uint* __restrict__ hin,     // bf16x2 [N][64]
                                                   const ushort* __restrict__ Wt,    // bf16 [128][128] (n-major)
                                                   const float* __restrict__ b,
                                                   const float* __restrict__ dinv,
                                                   uint* __restrict__ hout16,
                                                   const ushort* __restrict__ Wct,   // bf16 [16][128]
                                                   const float* __restrict__ bc,
                                                   float* __restrict__ outf, int N) {
    __shared__ __align__(16) ushort T[64][136];    // +8 pad: conflict-free b128 reads
    int tid  = threadIdx.x;
    int lane = tid & 63, wv = tid >> 6;
    int c0 = lane & 15, g = lane >> 4;
    long wrow = (long)blockIdx.x * 64 + wv * 16;
    long arow = wrow + c0; if (arow >= N) arow = N - 1;

    short8 a[4];
    const uint* hr = hin + (size_t)arow * 64;
    #pragma unroll
    for (int kk = 0; kk < 4; ++kk)
        a[kk] = *(const short8*)(hr + kk * 16 + g * 4);

    float dsc[4];
    #pragma unroll
    for (int j = 0; j < 4; ++j) {
        long r = wrow + g * 4 + j; if (r >= N) r = N - 1;
        dsc[j] = FUSE ? 1.f : dinv[r];
    }

    #pragma unroll
    for (int nt = 0; nt < 8; ++nt) {
        float bias = b[nt * 16 + c0];
        f32x4 acc = {bias, bias, bias, bias};
        const ushort* wb = Wt + (size_t)(nt * 16 + c0) * D + g * 8;
        #pragma unroll
        for (int kk = 0; kk < 4; ++kk) {
            short8 bf = *(const short8*)(wb + kk * 32);
            acc = __builtin_amdgcn_mfma_f32_16x16x32_bf16(a[kk], bf, acc, 0, 0, 0);
        }
        #pragma unroll
        for (int j = 0; j < 4; ++j)
            T[wv * 16 + g * 4 + j][nt * 16 + c0] = bf1(fmaxf(acc[j], 0.f) * dsc[j]);
    }
    __syncthreads();

    if (!FUSE) {
        int r = tid >> 2, q = tid & 3;
        long grow = (long)blockIdx.x * 64 + r;
        if (grow < N) {
            uint4* dstp = (uint4*)(hout16 + grow * 64 + q * 16);
            const uint4* srcp = (const uint4*)((const char*)&T[r][0] + q * 64);
            #pragma unroll
            for (int i = 0; i < 4; ++i) dstp[i] = srcp[i];
        }
    } else {
        float biasc = bc[c0];
        f32x4 acc2 = {biasc, biasc, biasc, biasc};
        #pragma unroll
        for (int kk = 0; kk < 4; ++kk) {
            short8 ta = *(const short8*)((const char*)&T[wv * 16 + c0][0] + kk * 64 + g * 16);
            short8 wc = *(const short8*)(Wct + (size_t)c0 * D + kk * 32 + g * 8);
            acc2 = __builtin_amdgcn_mfma_f32_16x16x32_bf16(ta, wc, acc2, 0, 0, 0);
        }
        #pragma unroll
        for (int j = 0; j < 4; ++j) {
            long grow = wrow + g * 4 + j;
            if (grow < N) outf[grow * C + c0] = acc2[j];
        }
    }
}

// ---------------------------------------------------------------- launch

extern "C" void kernel_launch(void* const* d_in, const int* in_sizes, int n_in,
                              void* d_out, int out_size, void* d_ws, size_t ws_size,
                              hipStream_t stream) {
    const int*   x    = (const int*)  d_in[0];
    const int*   ei   = (const int*)  d_in[1];   // [2,E]: first E = src, next E = dst
    const float* emb  = (const float*)d_in[2];
    const float* W0   = (const float*)d_in[3];
    const float* b0   = (const float*)d_in[4];
    const float* W1   = (const float*)d_in[5];
    const float* b1   = (const float*)d_in[6];
    const float* Wc   = (const float*)d_in[7];
    const float* bc   = (const float*)d_in[8];
    float* out = (float*)d_out;

    const int N  = in_sizes[0];
    const int E  = in_sizes[1] / 2;
    const int Et = E + N;

    const int* src = ei;
    const int* dst = ei + E;

    // bucket shift: width 2^shift, NB <= NBMAX  (N=50000 -> shift 7, NB=391)
    int shift = 7;
    while (((N + (1 << shift) - 1) >> shift) > NBMAX) shift++;
    const int NB = (N + (1 << shift) - 1) >> shift;

    char* p = (char*)d_ws;
    auto take = [&](size_t bytes) { char* q = p; p += (bytes + 255) & ~(size_t)255; return q; };
    int*    row_ptr = (int*)   take((size_t)(N + 1) * 4);
    float*  dinv    = (float*) take((size_t)N * 4);
    int*    bcnt    = (int*)   take((size_t)NBMAX * 4);
    int*    bbase   = (int*)   take((size_t)(NBMAX + 1) * 4);
    int*    bcur    = (int*)   take((size_t)NBMAX * 4);
    uint*   tmp     = (uint*)  take((size_t)E * 4);
    int*    col     = (int*)   take((size_t)Et * 4);
    ushort* Wt0     = (ushort*)take((size_t)D * D * 2);
    ushort* Wt1     = (ushort*)take((size_t)D * D * 2);
    ushort* Wct     = (ushort*)take((size_t)D * C * 2);
    uint*   hA16    = (uint*)  take((size_t)N * 64 * 4);
    uint*   hB16    = (uint*)  take((size_t)N * 64 * 4);

    const int BS = 256;
    const int EB = (int)(((long)E + 256 * VPT - 1) / (256 * VPT));

    hipMemsetAsync(bcnt, 0, NBMAX * 4, stream);
    k_bhist   <<<EB, BS, 0, stream>>>(dst, bcnt, E, shift);
    k_bscan   <<<1, NBMAX, 0, stream>>>(bcnt, bbase, bcur, NB);
    k_bscatter<<<EB, BS, 0, stream>>>(src, dst, bcur, tmp, E, shift);
    k_build   <<<NB, BS, 0, stream>>>(tmp, bbase, row_ptr, dinv, col, N, shift, NB, Et);
    k_embed   <<<((long)N * 16 + BS - 1) / BS, BS, 0, stream>>>(x, emb, dinv, hA16, N);
    k_wconv   <<<(D * D + 255) / 256, 256, 0, stream>>>(W0, W1, Wc, Wt0, Wt1, Wct);

    const int AGG_BLOCKS = 2048;
    const int NWAVES = AGG_BLOCKS * 4;
    const int GEMM_BLOCKS = (N + 63) / 64;

    // layer 0
    k_agg<<<AGG_BLOCKS, BS, 0, stream>>>(hA16, row_ptr, col, dinv, hB16, N, NWAVES);
    k_gemm_mfma<false><<<GEMM_BLOCKS, BS, 0, stream>>>(hB16, Wt0, b0, dinv, hA16, nullptr, nullptr, nullptr, N);
    // layer 1 + fused classifier
    k_agg<<<AGG_BLOCKS, BS, 0, stream>>>(hA16, row_ptr, col, dinv, hB16, N, NWAVES);
    k_gemm_mfma<true><<<GEMM_BLOCKS, BS, 0, stream>>>(hB16, Wt1, b1, dinv, nullptr, Wct, bc, out, N);
}